// Round 5
// baseline (1068.738 us; speedup 1.0000x reference)
//
#include <hip/hip_runtime.h>
#include <cstdint>
#include <cstddef>

// =====================================================================
// LENet block: x = MHA(LN(q), LN(kv)) + q ; x = MHA(LN(x),LN(x)) + x ;
//              x = NoisyTop2MoE(LN(x)) + x
// Round 7: GEMM staging rewritten to async global_load_lds (width 16).
//   - linear LDS tiles (row stride 32 u16 = 16 dwords): ds_read_b128
//     frag loads start at bank-group 16*(col&1)+4*quad -> 8 groups x 8
//     lanes = minimal for b128, conflict-free; no pad needed.
//   - 8 (split) / 4 (ffn) global_load_lds_dwordx4 per K-step replace
//     the global->VGPR->ds_write staging + its address VALU.
//   - slot map: thread t stages 16B slots t and t+256; slot s covers
//     LDS row s>>2, k-part (s&3)*8 (wave-uniform base + lane*16 rule).
// Round 6: ffn2 split-K x4; fused QKV projection launch; reg prefetch.
// Round 5: expert weights pre-transposed+converted to bf16 W^T (tcvt).
// Round 4: split-bf16 MFMA flash attention.
// Projections: split-bf16 (bf16x3) MFMA, ~4e-6 rel err, routing-safe.
// =====================================================================
#define JAX_THREEFRY_PARTITIONABLE 1

typedef unsigned short u16;
typedef unsigned int u32;
typedef __attribute__((ext_vector_type(8))) short bf16x8;   // 8 bf16 = 4 VGPR
typedef __attribute__((ext_vector_type(4))) float f32x4;

struct Ptr8 { u16* p[8]; };   // per-expert W^T bf16 buffers (by-value arg)

struct QkvArgs {              // fused QKV projection args (by-value)
  const u16* ah[3]; const u16* al[3];
  const u16* wh[3]; const u16* wl[3];
  const float* bias[3];
  float* c[3];
  int M[3];
};

__device__ __forceinline__ int imin_(int a, int b) { return a < b ? a : b; }

// async 16B global -> LDS (wave-uniform lds base + lane*16 semantics)
__device__ __forceinline__ void gl16_(const void* g, void* l) {
  __builtin_amdgcn_global_load_lds(
      (const __attribute__((address_space(1))) void*)g,
      (__attribute__((address_space(3))) void*)l, 16, 0, 0);
}

__device__ __forceinline__ u16 f2bf_(float f) {  // RNE float->bf16
  unsigned u = __float_as_uint(f);
  return (u16)((u + 0x7fffu + ((u >> 16) & 1u)) >> 16);
}
__device__ __forceinline__ float bf2f_(u16 h) {
  return __uint_as_float(((unsigned)h) << 16);
}

// split (a,b) into packed-u32 (hi,hi) and (lo,lo) bf16 pairs, low half = a
__device__ __forceinline__ void split2_(float a, float b, u32& hi, u32& lo) {
  u16 h0 = f2bf_(a), h1 = f2bf_(b);
  u16 l0 = f2bf_(a - bf2f_(h0)), l1 = f2bf_(b - bf2f_(h1));
  hi = (u32)h0 | ((u32)h1 << 16);
  lo = (u32)l0 | ((u32)l1 << 16);
}

union FragU {
  u32 w[4];
  uint4 q;
  bf16x8 v;
};

// ---------------- threefry2x32 (JAX-exact, 20 rounds) ----------------
__device__ __forceinline__ unsigned rotl32_(unsigned v, int d) {
  return (v << d) | (v >> (32 - d));
}

__device__ __forceinline__ void threefry2x32_(unsigned k0, unsigned k1,
                                              unsigned x0, unsigned x1,
                                              unsigned& o0, unsigned& o1) {
  unsigned ks2 = k0 ^ k1 ^ 0x1BD11BDAu;
  x0 += k0; x1 += k1;
#define TF_R(rot) { x0 += x1; x1 = rotl32_(x1, rot); x1 ^= x0; }
  TF_R(13) TF_R(15) TF_R(26) TF_R(6)
  x0 += k1;  x1 += ks2 + 1u;
  TF_R(17) TF_R(29) TF_R(16) TF_R(24)
  x0 += ks2; x1 += k0 + 2u;
  TF_R(13) TF_R(15) TF_R(26) TF_R(6)
  x0 += k0;  x1 += k1 + 3u;
  TF_R(17) TF_R(29) TF_R(16) TF_R(24)
  x0 += k1;  x1 += ks2 + 4u;
  TF_R(13) TF_R(15) TF_R(26) TF_R(6)
  x0 += ks2; x1 += k0 + 5u;
#undef TF_R
  o0 = x0; o1 = x1;
}

// XLA ErfInv32 (Giles polynomial) — matches lax.erf_inv on f32.
__device__ float erfinv_f32_(float x) {
  float w = -log1pf(-x * x);
  float p;
  if (w < 5.0f) {
    w -= 2.5f;
    p = 2.81022636e-08f;
    p = fmaf(p, w, 3.43273939e-07f);
    p = fmaf(p, w, -3.5233877e-06f);
    p = fmaf(p, w, -4.39150654e-06f);
    p = fmaf(p, w, 0.00021858087f);
    p = fmaf(p, w, -0.00125372503f);
    p = fmaf(p, w, -0.00417768164f);
    p = fmaf(p, w, 0.246640727f);
    p = fmaf(p, w, 1.50140941f);
  } else {
    w = sqrtf(w) - 3.0f;
    p = -0.000200214257f;
    p = fmaf(p, w, 0.000100950558f);
    p = fmaf(p, w, 0.00134934322f);
    p = fmaf(p, w, -0.00367342844f);
    p = fmaf(p, w, 0.00573950773f);
    p = fmaf(p, w, -0.0076224613f);
    p = fmaf(p, w, 0.00943887047f);
    p = fmaf(p, w, 1.00167406f);
    p = fmaf(p, w, 2.83297682f);
  }
  return p * x;
}

__device__ float bits_to_normal_(unsigned b) {
  const float lo = -0.99999994f;  // nextafter(-1, 0) in f32
  float f = __uint_as_float((b >> 9) | 0x3f800000u) - 1.0f;  // [0,1)
  float u = fmaxf(lo, f * 2.0f + lo);
  return 1.41421356237f * erfinv_f32_(u);
}

// normals for logits shape (2,1024,8) -> 16384 elems, key = (0,42)
__global__ __launch_bounds__(256) void noise_kernel(float* __restrict__ normals) {
  int i = blockIdx.x * 256 + threadIdx.x;
#if JAX_THREEFRY_PARTITIONABLE
  if (i < 16384) {
    unsigned o0, o1;
    threefry2x32_(0u, 42u, 0u, (unsigned)i, o0, o1);
    normals[i] = bits_to_normal_(o0 ^ o1);
  }
#else
  if (i < 8192) {
    unsigned o0, o1;
    threefry2x32_(0u, 42u, (unsigned)i, (unsigned)(i + 8192), o0, o1);
    normals[i] = bits_to_normal_(o0);
    normals[i + 8192] = bits_to_normal_(o1);
  }
#endif
}

// ---------------- block reduce (256 threads, wave64) -----------------
__device__ float block_reduce_sum_(float v) {
  for (int m = 1; m <= 32; m <<= 1) v += __shfl_xor(v, m, 64);
  __shared__ float red[4];
  int lane = threadIdx.x & 63, w = threadIdx.x >> 6;
  if (lane == 0) red[w] = v;
  __syncthreads();
  v = red[0] + red[1] + red[2] + red[3];
  __syncthreads();
  return v;
}

// ---------------- LayerNorm (fp32 out) -------------------------------
__global__ __launch_bounds__(256) void ln_kernel(
    const float* __restrict__ X, const float* __restrict__ g,
    const float* __restrict__ bta, float* __restrict__ Y) {
  int row = blockIdx.x;
  int t = threadIdx.x;
  const float4* xr = (const float4*)(X + (size_t)row * 1024);
  float4 v = xr[t];
  float s = v.x + v.y + v.z + v.w;
  s = block_reduce_sum_(s);
  float mean = s * (1.0f / 1024.0f);
  float dx = v.x - mean, dy = v.y - mean, dz = v.z - mean, dw = v.w - mean;
  float sq = dx * dx + dy * dy + dz * dz + dw * dw;
  sq = block_reduce_sum_(sq);
  float rstd = 1.0f / sqrtf(sq * (1.0f / 1024.0f) + 1e-5f);
  float4 gv = ((const float4*)g)[t];
  float4 bv = ((const float4*)bta)[t];
  float4 y;
  y.x = dx * rstd * gv.x + bv.x;
  y.y = dy * rstd * gv.y + bv.y;
  y.z = dz * rstd * gv.z + bv.z;
  y.w = dw * rstd * gv.w + bv.w;
  ((float4*)(Y + (size_t)row * 1024))[t] = y;
}

// ---------------- LayerNorm emitting split bf16 (hi,lo) --------------
__global__ __launch_bounds__(256) void ln_split_kernel(
    const float* __restrict__ X, const float* __restrict__ g,
    const float* __restrict__ bta, u16* __restrict__ Yh,
    u16* __restrict__ Yl) {
  int row = blockIdx.x;
  int t = threadIdx.x;
  const float4* xr = (const float4*)(X + (size_t)row * 1024);
  float4 v = xr[t];
  float s = v.x + v.y + v.z + v.w;
  s = block_reduce_sum_(s);
  float mean = s * (1.0f / 1024.0f);
  float dx = v.x - mean, dy = v.y - mean, dz = v.z - mean, dw = v.w - mean;
  float sq = dx * dx + dy * dy + dz * dz + dw * dw;
  sq = block_reduce_sum_(sq);
  float rstd = 1.0f / sqrtf(sq * (1.0f / 1024.0f) + 1e-5f);
  float4 gv = ((const float4*)g)[t];
  float4 bv = ((const float4*)bta)[t];
  float y[4];
  y[0] = dx * rstd * gv.x + bv.x;
  y[1] = dy * rstd * gv.y + bv.y;
  y[2] = dz * rstd * gv.z + bv.z;
  y[3] = dw * rstd * gv.w + bv.w;
  ushort4 h, l;
  u16* hp = (u16*)&h; u16* lp = (u16*)&l;
#pragma unroll
  for (int j = 0; j < 4; ++j) {
    u16 hh = f2bf_(y[j]);
    hp[j] = hh;
    lp[j] = f2bf_(y[j] - bf2f_(hh));
  }
  *(ushort4*)(Yh + (size_t)row * 1024 + t * 4) = h;
  *(ushort4*)(Yl + (size_t)row * 1024 + t * 4) = l;
}

// ---------------- fp32 -> (hi,lo) bf16 split, 4 elems/thread ---------
__global__ __launch_bounds__(256) void cvt_split_kernel(
    const float* __restrict__ src, u16* __restrict__ hi,
    u16* __restrict__ lo) {
  int i = (blockIdx.x * 256 + threadIdx.x) * 4;
  float4 v = *(const float4*)(src + i);
  float a[4] = {v.x, v.y, v.z, v.w};
  ushort4 h, l;
  u16* hp = (u16*)&h; u16* lp = (u16*)&l;
#pragma unroll
  for (int j = 0; j < 4; ++j) {
    u16 hh = f2bf_(a[j]);
    hp[j] = hh;
    lp[j] = f2bf_(a[j] - bf2f_(hh));
  }
  *(ushort4*)(hi + i) = h;
  *(ushort4*)(lo + i) = l;
}

// ---------- transpose+convert: fp32 [R][C] -> bf16 [C][R], 8 experts -
// 64x64 tile, LDS pad +1 (2-way max on transposed reads = free).
// Coalesced float4 in, coalesced ushort4 out.
__global__ __launch_bounds__(256) void tcvt_kernel(
    const float* __restrict__ src, Ptr8 dst, int R, int C) {
  __shared__ float tile[64][65];
  const int e = blockIdx.z;
  const float* S = src + (size_t)e * R * C;
  u16* D = dst.p[e];
  const int c0 = blockIdx.x * 64, r0 = blockIdx.y * 64;
  const int t = threadIdx.x;
  const int tr = t >> 4, tc = (t & 15) * 4;
#pragma unroll
  for (int p = 0; p < 4; ++p) {
    float4 v = *(const float4*)(S + (size_t)(r0 + p * 16 + tr) * C + c0 + tc);
    tile[p * 16 + tr][tc + 0] = v.x;
    tile[p * 16 + tr][tc + 1] = v.y;
    tile[p * 16 + tr][tc + 2] = v.z;
    tile[p * 16 + tr][tc + 3] = v.w;
  }
  __syncthreads();
#pragma unroll
  for (int p = 0; p < 4; ++p) {
    int oc = p * 16 + tr;
    ushort4 o;
    o.x = f2bf_(tile[tc + 0][oc]);
    o.y = f2bf_(tile[tc + 1][oc]);
    o.z = f2bf_(tile[tc + 2][oc]);
    o.w = f2bf_(tile[tc + 3][oc]);
    *(ushort4*)(D + (size_t)(c0 + oc) * R + r0 + tc) = o;
  }
}

// ============ split-bf16 MFMA GEMM: C = A @ W^T + bias (+resid) ======
// A: (hi,lo) bf16 [M][K] k-contig. W: (hi,lo) bf16 [N][K] k-contig.
// 128x128 tile, BK=32, 4 waves (2x2), each wave 4x4 frags of 16x16x32.
// 3 MFMA terms per frag pair: Ah*Bh + Ah*Bl + Al*Bh (fp32 acc).
// Staging: async global_load_lds 16B, linear LDS (32 u16 rows).
template<bool RESID>
__device__ __forceinline__ void split_gemm_body_(
    const u16* __restrict__ Ah, const u16* __restrict__ Al,
    const u16* __restrict__ Wh, const u16* __restrict__ Wl,
    const float* __restrict__ bias, const float* __restrict__ resid,
    float* __restrict__ C, int m0, int n0, int N, int K) {
  __shared__ __align__(16) u16 Ahs[128 * 32];
  __shared__ __align__(16) u16 Als[128 * 32];
  __shared__ __align__(16) u16 Bhs[128 * 32];
  __shared__ __align__(16) u16 Bls[128 * 32];
  const int t = threadIdx.x;
  const int lane = t & 63, wv = t >> 6;
  const int wm = (wv & 1) * 64, wn = (wv >> 1) * 64;
  const int col = lane & 15, quad = lane >> 4;
  f32x4 acc[4][4] = {};
  // slot map: thread t -> slots t and t+256; slot s: row s>>2, k (s&3)*8
  const int r0 = t >> 2, kq = (t & 3) * 8;
  const u16* pah0 = Ah + (size_t)(m0 + r0) * K + kq;
  const u16* pah1 = Ah + (size_t)(m0 + r0 + 64) * K + kq;
  const u16* pal0 = Al + (size_t)(m0 + r0) * K + kq;
  const u16* pal1 = Al + (size_t)(m0 + r0 + 64) * K + kq;
  const u16* pwh0 = Wh + (size_t)(n0 + r0) * K + kq;
  const u16* pwh1 = Wh + (size_t)(n0 + r0 + 64) * K + kq;
  const u16* pwl0 = Wl + (size_t)(n0 + r0) * K + kq;
  const u16* pwl1 = Wl + (size_t)(n0 + r0 + 64) * K + kq;
  u16* lah0 = &Ahs[t * 8];       u16* lah1 = &Ahs[(t + 256) * 8];
  u16* lal0 = &Als[t * 8];       u16* lal1 = &Als[(t + 256) * 8];
  u16* lbh0 = &Bhs[t * 8];       u16* lbh1 = &Bhs[(t + 256) * 8];
  u16* lbl0 = &Bls[t * 8];       u16* lbl1 = &Bls[(t + 256) * 8];
  for (int k0 = 0; k0 < K; k0 += 32) {
    gl16_(pah0, lah0); gl16_(pah1, lah1);
    gl16_(pal0, lal0); gl16_(pal1, lal1);
    gl16_(pwh0, lbh0); gl16_(pwh1, lbh1);
    gl16_(pwl0, lbl0); gl16_(pwl1, lbl1);
    pah0 += 32; pah1 += 32; pal0 += 32; pal1 += 32;
    pwh0 += 32; pwh1 += 32; pwl0 += 32; pwl1 += 32;
    __syncthreads();
    bf16x8 afh[4], afl[4], bfh[4], bfl[4];
#pragma unroll
    for (int i = 0; i < 4; ++i) {
      afh[i] = *(const bf16x8*)&Ahs[(wm + i * 16 + col) * 32 + quad * 8];
      afl[i] = *(const bf16x8*)&Als[(wm + i * 16 + col) * 32 + quad * 8];
    }
#pragma unroll
    for (int j = 0; j < 4; ++j) {
      bfh[j] = *(const bf16x8*)&Bhs[(wn + j * 16 + col) * 32 + quad * 8];
      bfl[j] = *(const bf16x8*)&Bls[(wn + j * 16 + col) * 32 + quad * 8];
    }
#pragma unroll
    for (int i = 0; i < 4; ++i) {
#pragma unroll
      for (int j = 0; j < 4; ++j) {
        acc[i][j] = __builtin_amdgcn_mfma_f32_16x16x32_bf16(afh[i], bfh[j], acc[i][j], 0, 0, 0);
        acc[i][j] = __builtin_amdgcn_mfma_f32_16x16x32_bf16(afh[i], bfl[j], acc[i][j], 0, 0, 0);
        acc[i][j] = __builtin_amdgcn_mfma_f32_16x16x32_bf16(afl[i], bfh[j], acc[i][j], 0, 0, 0);
      }
    }
    __syncthreads();
  }
  float bv[4];
#pragma unroll
  for (int j = 0; j < 4; ++j) bv[j] = bias[n0 + wn + j * 16 + col];
#pragma unroll
  for (int i = 0; i < 4; ++i) {
#pragma unroll
    for (int rr = 0; rr < 4; ++rr) {
      int m = m0 + wm + i * 16 + quad * 4 + rr;
      float* crow = C + (size_t)m * N;
      const float* rrow = RESID ? (resid + (size_t)m * N) : nullptr;
#pragma unroll
      for (int j = 0; j < 4; ++j) {
        int n = n0 + wn + j * 16 + col;
        float v = acc[i][j][rr] + bv[j];
        if (RESID) v += rrow[n];
        crow[n] = v;
      }
    }
  }
}

template<bool RESID>
__global__ __launch_bounds__(256) void split_gemm_nt(
    const u16* __restrict__ Ah, const u16* __restrict__ Al,
    const u16* __restrict__ Wh, const u16* __restrict__ Wl,
    const float* __restrict__ bias, const float* __restrict__ resid,
    float* __restrict__ C, int M, int N, int K) {
  (void)M;
  split_gemm_body_<RESID>(Ah, Al, Wh, Wl, bias, resid, C,
                          blockIdx.y * 128, blockIdx.x * 128, N, K);
}

// fused Q/K/V projections: blockIdx.z picks the projection.
__global__ __launch_bounds__(256) void split_gemm_qkv(QkvArgs a, int N, int K) {
  const int z = blockIdx.z;
  const int m0 = blockIdx.y * 128;
  if (m0 >= a.M[z]) return;
  split_gemm_body_<false>(a.ah[z], a.al[z], a.wh[z], a.wl[z], a.bias[z],
                          nullptr, a.c[z], m0, blockIdx.x * 128, N, K);
}

// ============ flash attention, split-bf16 MFMA, DH=64 ================
// Per block: 64 q rows x one (b,h); 4 waves, wave w owns q rows
// [w*16, w*16+16). KV tiles of 64.
//   S^T = K @ Q^T  (first operand = K frag -> C row = kv;
//                   second = Q frag -> C col = q). Lane (quad,col) then
//   holds S[q=wq0+col][kv = i*16+quad*4+r] in st[i][r] -> the entire
//   64-wide score row for ONE q-row is lane-local + xor(16,32).
//   P repack C-layout -> A-frag layout (lane needs P[col][ks*32+quad*8+e]):
//     source i    = 2*ks + (quad>>1)
//     source quad = (2*quad + (w>>1)) & 3   (w = target u32 word 0..3)
//     word pair   = w & 1
//   done with 32 lane shuffles (16 hi + 16 lo), no LDS round-trip.
//   PV: O[q][dh] via first = P frag, second = V^T (staged [dh][kv] split).
// 3-term split products throughout (err ~2^-16, routing-safe).
// Emits (hi,lo) bf16 split output for the following split GEMM.
__global__ __launch_bounds__(256) void attn_kernel(
    const float* __restrict__ QP, const float* __restrict__ KP,
    const float* __restrict__ VP, u16* __restrict__ AOh,
    u16* __restrict__ AOl, int nq, int nkv) {
  // stride 72 u16 = 36 dwords (odd multiple of 4 -> rows walk bank groups)
  __shared__ __align__(16) u16 Ksh[64 * 72];
  __shared__ __align__(16) u16 Ksl[64 * 72];
  __shared__ __align__(16) u16 Vth[64 * 72];
  __shared__ __align__(16) u16 Vtl[64 * 72];
  const int t = threadIdx.x;
  const int lane = t & 63, wv = t >> 6;
  const int col = lane & 15, quad = lane >> 4;
  const int bh = blockIdx.x;
  const int b = bh >> 4, h = bh & 15;
  const int q0 = blockIdx.y * 64;
  const int wq0 = wv * 16;

  // ---- preload this wave's Q fragments (B operand), scaled 1/8 ----
  bf16x8 qbh[2], qbl[2];
  {
    const float* qsrc =
        QP + (size_t)(b * nq + q0 + wq0 + col) * 1024 + h * 64 + quad * 8;
#pragma unroll
    for (int ks = 0; ks < 2; ++ks) {
      float4 f0 = *(const float4*)(qsrc + ks * 32);
      float4 f1 = *(const float4*)(qsrc + ks * 32 + 4);
      float qf[8] = {f0.x, f0.y, f0.z, f0.w, f1.x, f1.y, f1.z, f1.w};
      FragU uh, ul;
#pragma unroll
      for (int w = 0; w < 4; ++w)
        split2_(qf[2 * w] * 0.125f, qf[2 * w + 1] * 0.125f, uh.w[w], ul.w[w]);
      qbh[ks] = uh.v;
      qbl[ks] = ul.v;
    }
  }

  f32x4 o[4] = {};
  float mi = -INFINITY, li = 0.0f;

  const int kr = t >> 2, kc = (t & 3) * 16;     // K stage: row, col base
  const int vg = t >> 5, vr = (t & 31) * 2;     // V stage: col grp, row pair

  for (int kv0 = 0; kv0 < nkv; kv0 += 64) {
    // ---- stage K tile [64 kv][64 dh] as split bf16, row-major ----
    {
      const float* ksrc =
          KP + (size_t)(b * nkv + kv0 + kr) * 1024 + h * 64 + kc;
      float4 f0 = *(const float4*)(ksrc);
      float4 f1 = *(const float4*)(ksrc + 4);
      float4 f2 = *(const float4*)(ksrc + 8);
      float4 f3 = *(const float4*)(ksrc + 12);
      float kf[16] = {f0.x, f0.y, f0.z, f0.w, f1.x, f1.y, f1.z, f1.w,
                      f2.x, f2.y, f2.z, f2.w, f3.x, f3.y, f3.z, f3.w};
      FragU h0, h1, l0, l1;
#pragma unroll
      for (int w = 0; w < 4; ++w) {
        split2_(kf[2 * w], kf[2 * w + 1], h0.w[w], l0.w[w]);
        split2_(kf[8 + 2 * w], kf[9 + 2 * w], h1.w[w], l1.w[w]);
      }
      *(uint4*)&Ksh[kr * 72 + kc] = h0.q;
      *(uint4*)&Ksh[kr * 72 + kc + 8] = h1.q;
      *(uint4*)&Ksl[kr * 72 + kc] = l0.q;
      *(uint4*)&Ksl[kr * 72 + kc + 8] = l1.q;
    }
    // ---- stage V transposed [64 dh][64 kv], split bf16 ----
    {
      const float* vsrc =
          VP + (size_t)(b * nkv + kv0 + vr) * 1024 + h * 64 + vg * 8;
      float4 a0 = *(const float4*)(vsrc);
      float4 a1 = *(const float4*)(vsrc + 4);
      float4 b0 = *(const float4*)(vsrc + 1024);
      float4 b1 = *(const float4*)(vsrc + 1028);
      float va[8] = {a0.x, a0.y, a0.z, a0.w, a1.x, a1.y, a1.z, a1.w};
      float vb[8] = {b0.x, b0.y, b0.z, b0.w, b1.x, b1.y, b1.z, b1.w};
#pragma unroll
      for (int e = 0; e < 8; ++e) {
        u32 hh, ll;
        split2_(va[e], vb[e], hh, ll);  // low u16 = row vr (even kv)
        *(u32*)&Vth[(vg * 8 + e) * 72 + vr] = hh;
        *(u32*)&Vtl[(vg * 8 + e) * 72 + vr] = ll;
      }
    }
    __syncthreads();

    // ---- S^T = K @ Q^T, 3-term split ----
    f32x4 st[4] = {};
#pragma unroll
    for (int ks = 0; ks < 2; ++ks) {
      bf16x8 kah[4], kal[4];
#pragma unroll
      for (int i = 0; i < 4; ++i) {
        kah[i] = *(const bf16x8*)&Ksh[(i * 16 + col) * 72 + ks * 32 + quad * 8];
        kal[i] = *(const bf16x8*)&Ksl[(i * 16 + col) * 72 + ks * 32 + quad * 8];
      }
#pragma unroll
      for (int i = 0; i < 4; ++i) {
        st[i] = __builtin_amdgcn_mfma_f32_16x16x32_bf16(kah[i], qbh[ks], st[i], 0, 0, 0);
        st[i] = __builtin_amdgcn_mfma_f32_16x16x32_bf16(kah[i], qbl[ks], st[i], 0, 0, 0);
        st[i] = __builtin_amdgcn_mfma_f32_16x16x32_bf16(kal[i], qbh[ks], st[i], 0, 0, 0);
      }
    }

    // ---- online softmax: full score row is lane-local (+quad xor) ----
    float tmax = st[0][0];
#pragma unroll
    for (int i = 0; i < 4; ++i)
#pragma unroll
      for (int r = 0; r < 4; ++r) tmax = fmaxf(tmax, st[i][r]);
    tmax = fmaxf(tmax, __shfl_xor(tmax, 16, 64));
    tmax = fmaxf(tmax, __shfl_xor(tmax, 32, 64));
    float mnew = fmaxf(mi, tmax);
    float alpha = __expf(mi - mnew);
    float tsum = 0.0f;
#pragma unroll
    for (int i = 0; i < 4; ++i) {
#pragma unroll
      for (int r = 0; r < 4; ++r) {
        float p = __expf(st[i][r] - mnew);
        st[i][r] = p;
        tsum += p;
      }
    }
    tsum += __shfl_xor(tsum, 16, 64);
    tsum += __shfl_xor(tsum, 32, 64);
    li = li * alpha + tsum;
    mi = mnew;
    // rescale O: row of o component r is q-row quad*4+r; alpha for that
    // row lives in lanes with col == quad*4+r (replicated across quads).
    float alr[4];
#pragma unroll
    for (int r = 0; r < 4; ++r)
      alr[r] = __shfl(alpha, (lane & 48) | (quad * 4 + r), 64);
#pragma unroll
    for (int j = 0; j < 4; ++j)
#pragma unroll
      for (int r = 0; r < 4; ++r) o[j][r] *= alr[r];

    // ---- P -> split bf16, pack pairs, redistribute to A-frag layout ----
    u32 pkh[4][2], pkl[4][2];
#pragma unroll
    for (int i = 0; i < 4; ++i)
#pragma unroll
      for (int w = 0; w < 2; ++w)
        split2_(st[i][2 * w], st[i][2 * w + 1], pkh[i][w], pkl[i][w]);
    u32 APh[2][4], APl[2][4];
    const int par = quad >> 1;
#pragma unroll
    for (int i = 0; i < 4; ++i) {
#pragma unroll
      for (int w01 = 0; w01 < 2; ++w01) {
#pragma unroll
        for (int dw = 0; dw < 2; ++dw) {
          int src = (((2 * quad + dw) & 3) << 4) | col;
          u32 vh = (u32)__shfl((int)pkh[i][w01], src, 64);
          u32 vl = (u32)__shfl((int)pkl[i][w01], src, 64);
          if ((i & 1) == par) {
            APh[i >> 1][dw * 2 + w01] = vh;
            APl[i >> 1][dw * 2 + w01] = vl;
          }
        }
      }
    }

    // ---- O += P @ V (3-term split) ----
#pragma unroll
    for (int ks = 0; ks < 2; ++ks) {
      FragU fh, fl;
#pragma unroll
      for (int w = 0; w < 4; ++w) { fh.w[w] = APh[ks][w]; fl.w[w] = APl[ks][w]; }
      bf16x8 pah = fh.v, pal = fl.v;
#pragma unroll
      for (int j = 0; j < 4; ++j) {
        bf16x8 vbh = *(const bf16x8*)&Vth[(j * 16 + col) * 72 + ks * 32 + quad * 8];
        bf16x8 vbl = *(const bf16x8*)&Vtl[(j * 16 + col) * 72 + ks * 32 + quad * 8];
        o[j] = __builtin_amdgcn_mfma_f32_16x16x32_bf16(pah, vbh, o[j], 0, 0, 0);
        o[j] = __builtin_amdgcn_mfma_f32_16x16x32_bf16(pah, vbl, o[j], 0, 0, 0);
        o[j] = __builtin_amdgcn_mfma_f32_16x16x32_bf16(pal, vbh, o[j], 0, 0, 0);
      }
    }
    __syncthreads();
  }

  // ---- epilogue: 1/l per row, emit (hi,lo) split bf16 ----
  float inv = 1.0f / li;
  float ivr[4];
#pragma unroll
  for (int r = 0; r < 4; ++r)
    ivr[r] = __shfl(inv, (lane & 48) | (quad * 4 + r), 64);
#pragma unroll
  for (int r = 0; r < 4; ++r) {
    size_t base =
        (size_t)(b * nq + q0 + wq0 + quad * 4 + r) * 1024 + h * 64 + col;
#pragma unroll
    for (int j = 0; j < 4; ++j) {
      float v = o[j][r] * ivr[r];
      u16 hh = f2bf_(v);
      AOh[base + j * 16] = hh;
      AOl[base + j * 16] = f2bf_(v - bf2f_(hh));
    }
  }
}

// ---------------- router: logits & noise_logits (N=8 each) -----------
__global__ __launch_bounds__(256) void router_kernel(
    const float* __restrict__ xm, const float* __restrict__ rw,
    const float* __restrict__ rb, const float* __restrict__ nw,
    const float* __restrict__ nb, float* __restrict__ logits,
    float* __restrict__ nlogits) {
  int row = blockIdx.x, t = threadIdx.x;
  const float* x = xm + (size_t)row * 1024;
  float accl[8] = {}, accn[8] = {};
  for (int d = t; d < 1024; d += 256) {
    float xv = x[d];
#pragma unroll
    for (int e = 0; e < 8; ++e) {
      accl[e] += xv * rw[e * 1024 + d];
      accn[e] += xv * nw[e * 1024 + d];
    }
  }
  __shared__ float red[16][4];
  int lane = t & 63, w = t >> 6;
#pragma unroll
  for (int e = 0; e < 8; ++e) {
    float v = accl[e];
    for (int m = 1; m <= 32; m <<= 1) v += __shfl_xor(v, m, 64);
    if (lane == 0) red[e][w] = v;
    float v2 = accn[e];
    for (int m = 1; m <= 32; m <<= 1) v2 += __shfl_xor(v2, m, 64);
    if (lane == 0) red[8 + e][w] = v2;
  }
  __syncthreads();
  if (t < 8)
    logits[row * 8 + t] = red[t][0] + red[t][1] + red[t][2] + red[t][3] + rb[t];
  else if (t < 16)
    nlogits[row * 8 + t - 8] =
        red[t][0] + red[t][1] + red[t][2] + red[t][3] + nb[t - 8];
}

// ---------------- routing: noisy top-2, probs, expert counts ---------
__global__ __launch_bounds__(256) void route_kernel(
    const float* __restrict__ logits, const float* __restrict__ nlogits,
    const float* __restrict__ normals, int* __restrict__ routei,
    float* __restrict__ routep, int* __restrict__ cnt) {
  int bt = blockIdx.x * 256 + threadIdx.x;
  if (bt >= 2048) return;
  float noisy[8];
#pragma unroll
  for (int e = 0; e < 8; ++e) {
    float nl = nlogits[bt * 8 + e];
    float sp = fmaxf(nl, 0.0f) + log1pf(expf(-fabsf(nl)));  // softplus
    noisy[e] = logits[bt * 8 + e] + normals[bt * 8 + e] * sp;
  }
  int i1 = 0; float n1 = noisy[0];
#pragma unroll
  for (int e = 1; e < 8; ++e) if (noisy[e] > n1) { n1 = noisy[e]; i1 = e; }
  int i2 = -1; float n2 = -INFINITY;
#pragma unroll
  for (int e = 0; e < 8; ++e)
    if (e != i1 && noisy[e] > n2) { n2 = noisy[e]; i2 = e; }
  float e2 = expf(n2 - n1);
  float denom = 1.0f + e2;
  routei[bt * 2 + 0] = i1; routei[bt * 2 + 1] = i2;
  routep[bt * 2 + 0] = 1.0f / denom; routep[bt * 2 + 1] = e2 / denom;
  atomicAdd(&cnt[i1], 1);
  atomicAdd(&cnt[i2], 1);
}

__global__ void zero_kernel(int* __restrict__ cnt) {
  if (threadIdx.x < 8) cnt[threadIdx.x] = 0;
}

__global__ void offs_kernel(const int* __restrict__ cnt, int* __restrict__ offs,
                            int* __restrict__ fill) {
  if (threadIdx.x == 0 && blockIdx.x == 0) {
    int o = 0;
    for (int e = 0; e < 8; ++e) { offs[e] = o; o += cnt[e]; fill[e] = 0; }
  }
}

__global__ __launch_bounds__(256) void fill_kernel(
    const int* __restrict__ routei, const float* __restrict__ routep,
    const int* __restrict__ offs, int* __restrict__ fill,
    int* __restrict__ alist, float* __restrict__ aprob) {
  int bt = blockIdx.x * 256 + threadIdx.x;
  if (bt >= 2048) return;
#pragma unroll
  for (int s = 0; s < 2; ++s) {
    int e = routei[bt * 2 + s];
    int pos = offs[e] + atomicAdd(&fill[e], 1);
    alist[pos] = bt;
    aprob[pos] = routep[bt * 2 + s];
  }
}

__global__ __launch_bounds__(256) void copy_kernel(const float* __restrict__ src,
                                                   float* __restrict__ dst) {
  int i = blockIdx.x * 256 + threadIdx.x;
  ((float4*)dst)[i] = ((const float4*)src)[i];
}

// fp32 -> bf16 convert (hi only), 4 elems/thread
__global__ __launch_bounds__(256) void f2bf_kernel(const float* __restrict__ src,
                                                   u16* __restrict__ dst) {
  int i = (blockIdx.x * 256 + threadIdx.x) * 4;
  float4 v = *(const float4*)(src + i);
  ushort4 o;
  o.x = f2bf_(v.x); o.y = f2bf_(v.y); o.z = f2bf_(v.z); o.w = f2bf_(v.w);
  *(ushort4*)(dst + i) = o;
}

__device__ __forceinline__ float gelu_exact_(float x) {
  return 0.5f * x * (1.0f + erff(x * 0.70710678f));
}

// ===================== bf16 MFMA expert GEMMs ========================
// NT structure on pre-transposed bf16 W^T (k-contiguous both operands).
// 128x128 tile, BK=32, async global_load_lds staging, linear LDS.
__global__ __launch_bounds__(256) void ffn1_mfma(
    const u16* __restrict__ Xb, Ptr8 w1t, const float* __restrict__ B1,
    u16* __restrict__ H, const int* __restrict__ alist,
    const int* __restrict__ cnt, const int* __restrict__ offs) {
  const int e = blockIdx.z;
  const int ce = cnt[e];
  const int m0 = blockIdx.y * 128;
  if (m0 >= ce) return;
  const int off = offs[e];
  const int n0 = blockIdx.x * 128;
  const u16* __restrict__ WT = w1t.p[e];   // [4096][1024] bf16 k-contig
  __shared__ __align__(16) u16 As[128 * 32];
  __shared__ __align__(16) u16 Bs[128 * 32];
  const int t = threadIdx.x;
  const int lane = t & 63, wv = t >> 6;
  const int wm = (wv & 1) * 64, wn = (wv >> 1) * 64;
  const int col = lane & 15, quad = lane >> 4;
  f32x4 acc[4][4] = {};
  const int r0 = t >> 2, kq = (t & 3) * 8;
  const int arow0 = alist[off + imin_(m0 + r0, ce - 1)];
  const int arow1 = alist[off + imin_(m0 + r0 + 64, ce - 1)];
  const u16* pa0 = Xb + (size_t)arow0 * 1024 + kq;
  const u16* pa1 = Xb + (size_t)arow1 * 1024 + kq;
  const u16* pw0 = WT + (size_t)(n0 + r0) * 1024 + kq;
  const u16* pw1 = WT + (size_t)(n0 + r0 + 64) * 1024 + kq;
  u16* la0 = &As[t * 8]; u16* la1 = &As[(t + 256) * 8];
  u16* lb0 = &Bs[t * 8]; u16* lb1 = &Bs[(t + 256) * 8];
  for (int k0 = 0; k0 < 1024; k0 += 32) {
    gl16_(pa0, la0); gl16_(pa1, la1);
    gl16_(pw0, lb0); gl16_(pw1, lb1);
    pa0 += 32; pa1 += 32; pw0 += 32; pw1 += 32;
    __syncthreads();
    bf16x8 af[4], bf[4];
#pragma unroll
    for (int i = 0; i < 4; ++i)
      af[i] = *(const bf16x8*)&As[(wm + i * 16 + col) * 32 + quad * 8];
#pragma unroll
    for (int j = 0; j < 4; ++j)
      bf[j] = *(const bf16x8*)&Bs[(wn + j * 16 + col) * 32 + quad * 8];
#pragma unroll
    for (int i = 0; i < 4; ++i)
#pragma unroll
      for (int j = 0; j < 4; ++j)
        acc[i][j] = __builtin_amdgcn_mfma_f32_16x16x32_bf16(af[i], bf[j], acc[i][j], 0, 0, 0);
    __syncthreads();
  }
#pragma unroll
  for (int j = 0; j < 4; ++j) {
    int n = n0 + wn + j * 16 + col;
    float bv = B1[(size_t)e * 4096 + n];
#pragma unroll
    for (int i = 0; i < 4; ++i) {
#pragma unroll
      for (int r2 = 0; r2 < 4; ++r2) {
        int m = m0 + wm + i * 16 + quad * 4 + r2;
        if (m < ce) {
          float v = gelu_exact_(acc[i][j][r2] + bv);
          H[(size_t)(off + m) * 4096 + n] = f2bf_(v);
        }
      }
    }
  }
}

// ffn2 with split-K x4: blockIdx.y = (m-tile << 2) | ksplit.
// Each chunk computes K in [ks*1024, ks*1024+1024) and atomicAdds its
// partial; bias is added by the ks==0 chunk only.
__global__ __launch_bounds__(256) void ffn2_mfma(
    const u16* __restrict__ H, Ptr8 w2t, const float* __restrict__ B2,
    float* __restrict__ Out, const int* __restrict__ alist,
    const float* __restrict__ aprob, const int* __restrict__ cnt,
    const int* __restrict__ offs) {
  const int e = blockIdx.z;
  const int ce = cnt[e];
  const int mt = blockIdx.y >> 2, ks = blockIdx.y & 3;
  const int m0 = mt * 128;
  if (m0 >= ce) return;
  const int off = offs[e];
  const int n0 = blockIdx.x * 128;
  const u16* __restrict__ WT = w2t.p[e];   // [1024][4096] bf16 k-contig
  __shared__ __align__(16) u16 As[128 * 32];
  __shared__ __align__(16) u16 Bs[128 * 32];
  const int t = threadIdx.x;
  const int lane = t & 63, wv = t >> 6;
  const int wm = (wv & 1) * 64, wn = (wv >> 1) * 64;
  const int col = lane & 15, quad = lane >> 4;
  f32x4 acc[4][4] = {};
  const int r0 = t >> 2, kq = (t & 3) * 8;
  const u16* pa0 =
      H + (size_t)(off + imin_(m0 + r0, ce - 1)) * 4096 + ks * 1024 + kq;
  const u16* pa1 =
      H + (size_t)(off + imin_(m0 + r0 + 64, ce - 1)) * 4096 + ks * 1024 + kq;
  const u16* pw0 = WT + (size_t)(n0 + r0) * 4096 + ks * 1024 + kq;
  const u16* pw1 = WT + (size_t)(n0 + r0 + 64) * 4096 + ks * 1024 + kq;
  u16* la0 = &As[t * 8]; u16* la1 = &As[(t + 256) * 8];
  u16* lb0 = &Bs[t * 8]; u16* lb1 = &Bs[(t + 256) * 8];
  for (int k0 = 0; k0 < 1024; k0 += 32) {
    gl16_(pa0, la0); gl16_(pa1, la1);
    gl16_(pw0, lb0); gl16_(pw1, lb1);
    pa0 += 32; pa1 += 32; pw0 += 32; pw1 += 32;
    __syncthreads();
    bf16x8 af[4], bf[4];
#pragma unroll
    for (int i = 0; i < 4; ++i)
      af[i] = *(const bf16x8*)&As[(wm + i * 16 + col) * 32 + quad * 8];
#pragma unroll
    for (int j = 0; j < 4; ++j)
      bf[j] = *(const bf16x8*)&Bs[(wn + j * 16 + col) * 32 + quad * 8];
#pragma unroll
    for (int i = 0; i < 4; ++i)
#pragma unroll
      for (int j = 0; j < 4; ++j)
        acc[i][j] = __builtin_amdgcn_mfma_f32_16x16x32_bf16(af[i], bf[j], acc[i][j], 0, 0, 0);
    __syncthreads();
  }
  float bv[4];
#pragma unroll
  for (int j = 0; j < 4; ++j)
    bv[j] = (ks == 0) ? B2[(size_t)e * 1024 + n0 + wn + j * 16 + col] : 0.0f;
#pragma unroll
  for (int i = 0; i < 4; ++i) {
#pragma unroll
    for (int r2 = 0; r2 < 4; ++r2) {
      int m = m0 + wm + i * 16 + quad * 4 + r2;
      if (m < ce) {
        int aidx = off + m;
        int tok = alist[aidx];
        float p = aprob[aidx];
        float* orow = Out + (size_t)tok * 1024;
#pragma unroll
        for (int j = 0; j < 4; ++j) {
          int n = n0 + wn + j * 16 + col;
          atomicAdd(&orow[n], p * (acc[i][j][r2] + bv[j]));
        }
      }
    }
  }
}

// =====================================================================
extern "C" void kernel_launch(void* const* d_in, const int* in_sizes, int n_in,
                              void* d_out, int out_size, void* d_ws, size_t ws_size,
                              hipStream_t stream) {
  (void)in_sizes; (void)n_in; (void)out_size; (void)ws_size;
  const float* q        = (const float*)d_in[0];
  const float* kv       = (const float*)d_in[1];
  const float* ln_cq_g  = (const float*)d_in[2];
  const float* ln_cq_b  = (const float*)d_in[3];
  const float* ln_ckv_g = (const float*)d_in[4];
  const float* ln_ckv_b = (const float*)d_in[5];
  const float* ln_s_g   = (const float*)d_in[6];
  const float* ln_s_b   = (const float*)d_in[7];
  const float* ln_m_g   = (const float*)d_in[8];
  const float* ln_m_b   = (const float*)d_in[9];
  const float* ca_in_w  = (const float*)d_in[10];
  const float* ca_in_b  = (const float*)d_in[11];
  const float* ca_out_w = (const float*)d_in[12];
  const float* ca_out_b = (const float*)d_in[13];
  const float* sa_in_w  = (const float*)d_in[14];
  const float* sa_in_b  = (const float*)d_in[15];
  const float* sa_out_w = (const float*)d_in[16];
  const float* sa_out_b = (const float*)d_in[17];
  const float* moe_rw   = (const float*)d_in[18];
  const float* moe_rb   = (const float*)d_in[19];
  const float* moe_nw   = (const float*)d_in[20];
  const float* moe_nb   = (const float*)d_in[21];
  const float* moe_w1   = (const float*)d_in[22];
  const float* moe_b1   = (const float*)d_in[23];
  const float* moe_w2   = (const float*)d_in[24];
  const float* moe_b2   = (const float*)d_in[25];
  float* out = (float*)d_out;

  // -------- workspace layout (floats). Peak ~112.5 MB. --------
  float* ws = (float*)d_ws;
  const size_t MEG = 1u << 20;
  float* x1   = ws;               // 2M fl
  float* x2   = ws + 2 * MEG;     // 2M fl
  float* xm   = ws + 4 * MEG;     // 2M fl
  u16*   aoh  = (u16*)(ws + 6 * MEG);  // 2M el (attn out hi)
  u16*   aol  = (u16*)(ws + 7 * MEG);  // 2M el (attn out lo)
  float* misc = ws + 8 * MEG;
  float* normals = misc;                      // 16384
  float* logits  = misc + 16384;              // 16384
  float* nlogits = misc + 32768;              // 16384
  float* routep  = misc + 49152;              // 4096
  float* aprob   = misc + 53248;              // 4096
  int*   routei  = (int*)(misc + 57344);      // 4096
  int*   alist   = (int*)(misc + 61440);      // 4096
  int*   cnt     = (int*)(misc + 65536);      // 8
  int*   offs    = cnt + 8;                   // 8
  int*   fillc   = cnt + 16;                  // 8
  float* RA = ws + 8 * MEG + 131072;          // 20M fl, phase-reused
  // attn phases:
  u16*   w1h = (u16*)RA;                    // 3M el (in-proj weights hi)
  u16*   w1l = (u16*)(RA + (3 * MEG) / 2);  // 3M el
  u16*   w2h = (u16*)(RA + 3 * MEG);        // 1M el (out-proj hi)
  u16*   w2l = (u16*)(RA + 3 * MEG + MEG / 2);
  u16*   a1h = (u16*)(RA + 4 * MEG);        // 2M el (lnq / xs hi)
  u16*   a1l = (u16*)(RA + 5 * MEG);
  u16*   a2h = (u16*)(RA + 6 * MEG);        // 4M el (lnkv hi; cross only)
  u16*   a2l = (u16*)(RA + 8 * MEG);
  float* qp  = RA + 10 * MEG;               // 2M fl
  float* kp  = RA + 12 * MEG;               // 4M fl (self: 2M)
  float* vp  = RA + 16 * MEG;               // 4M fl (self: 2M)
  // moe phase:
  u16*   xb  = (u16*)RA;                    // 2M el bf16
  u16*   hb  = (u16*)(RA + 1 * MEG);        // 16M el bf16 (ends RA+9M fl)
  // W^T bf16 buffers (8 x 4M el = 8 MB each), in MoE-phase-dead regions:
  //   e0..e4: RA + 9M..19M fl ; e5: x1 ; e6: xm ; e7: aoh+aol
  Ptr8 wt;
  wt.p[0] = (u16*)(RA + 9 * MEG);
  wt.p[1] = (u16*)(RA + 11 * MEG);
  wt.p[2] = (u16*)(RA + 13 * MEG);
  wt.p[3] = (u16*)(RA + 15 * MEG);
  wt.p[4] = (u16*)(RA + 17 * MEG);
  wt.p[5] = (u16*)x1;
  wt.p[6] = (u16*)xm;
  wt.p[7] = (u16*)(ws + 6 * MEG);

  dim3 blk(256);

  zero_kernel<<<dim3(1), blk, 0, stream>>>(cnt);
  noise_kernel<<<dim3(64), blk, 0, stream>>>(normals);

  // ---- cross attention ----
  cvt_split_kernel<<<dim3(3072), blk, 0, stream>>>(ca_in_w, w1h, w1l);
  cvt_split_kernel<<<dim3(1024), blk, 0, stream>>>(ca_out_w, w2h, w2l);
  ln_split_kernel<<<dim3(2048), blk, 0, stream>>>(q, ln_cq_g, ln_cq_b, a1h, a1l);
  ln_split_kernel<<<dim3(4096), blk, 0, stream>>>(kv, ln_ckv_g, ln_ckv_b, a2h, a2l);
  {
    QkvArgs qa;
    qa.ah[0] = a1h; qa.al[0] = a1l;
    qa.ah[1] = a2h; qa.al[1] = a2l;
    qa.ah[2] = a2h; qa.al[2] = a2l;
    for (int z = 0; z < 3; ++z) {
      qa.wh[z] = w1h + (size_t)z * MEG;
      qa.wl[z] = w1l + (size_t)z * MEG;
      qa.bias[z] = ca_in_b + z * 1024;
    }
    qa.c[0] = qp; qa.c[1] = kp; qa.c[2] = vp;
    qa.M[0] = 2048; qa.M[1] = 4096; qa.M[2] = 4096;
    split_gemm_qkv<<<dim3(8, 32, 3), blk, 0, stream>>>(qa, 1024, 1024);
  }
  attn_kernel<<<dim3(32, 16), blk, 0, stream>>>(qp, kp, vp, aoh, aol, 1024, 2048);
  split_gemm_nt<true><<<dim3(8, 16), blk, 0, stream>>>(
      aoh, aol, w2h, w2l, ca_out_b, q, x1, 2048, 1024, 1024);

  // ---- self attention ----
  cvt_split_kernel<<<dim3(3072), blk, 0, stream>>>(sa_in_w, w1h, w1l);
  cvt_split_kernel<<<dim3(1024), blk, 0, stream>>>(sa_out_w, w2h, w2l);
  ln_split_kernel<<<dim3(2048), blk, 0, stream>>>(x1, ln_s_g, ln_s_b, a1h, a1l);
  {
    QkvArgs qa;
    for (int z = 0; z < 3; ++z) {
      qa.ah[z] = a1h; qa.al[z] = a1l;
      qa.wh[z] = w1h + (size_t)z * MEG;
      qa.wl[z] = w1l + (size_t)z * MEG;
      qa.bias[z] = sa_in_b + z * 1024;
      qa.M[z] = 2048;
    }
    qa.c[0] = qp; qa.c[1] = kp; qa.c[2] = vp;
    split_gemm_qkv<<<dim3(8, 16, 3), blk, 0, stream>>>(qa, 1024, 1024);
  }
  attn_kernel<<<dim3(32, 16), blk, 0, stream>>>(qp, kp, vp, aoh, aol, 1024, 1024);
  split_gemm_nt<true><<<dim3(8, 16), blk, 0, stream>>>(
      aoh, aol, w2h, w2l, sa_out_b, x1, x2, 2048, 1024, 1024);

  // ---- MoE ----
  ln_kernel<<<dim3(2048), blk, 0, stream>>>(x2, ln_m_g, ln_m_b, xm);
  f2bf_kernel<<<dim3(2048), blk, 0, stream>>>(xm, xb);
  router_kernel<<<dim3(2048), blk, 0, stream>>>(xm, moe_rw, moe_rb, moe_nw, moe_nb, logits, nlogits);
  route_kernel<<<dim3(8), blk, 0, stream>>>(logits, nlogits, normals, routei, routep, cnt);
  offs_kernel<<<dim3(1), blk, 0, stream>>>(cnt, offs, fillc);
  fill_kernel<<<dim3(8), blk, 0, stream>>>(routei, routep, offs, fillc, alist, aprob);
  copy_kernel<<<dim3(2048), blk, 0, stream>>>(x2, out);  // residual base
  // W1 [e][1024][4096] -> w1T [e][4096][1024] bf16 (x1/xm/aoh dead now)
  tcvt_kernel<<<dim3(64, 16, 8), blk, 0, stream>>>(moe_w1, wt, 1024, 4096);
  ffn1_mfma<<<dim3(32, 16, 8), blk, 0, stream>>>(xb, wt, moe_b1, hb, alist, cnt, offs);
  // W2 [e][4096][1024] -> w2T [e][1024][4096] bf16 (reuses same buffers)
  tcvt_kernel<<<dim3(16, 64, 8), blk, 0, stream>>>(moe_w2, wt, 4096, 1024);
  ffn2_mfma<<<dim3(8, 64, 8), blk, 0, stream>>>(hb, wt, moe_b2, out, alist, aprob, cnt, offs);
}

// Round 6
// 980.154 us; speedup vs baseline: 1.0904x; 1.0904x over previous
//
#include <hip/hip_runtime.h>
#include <cstdint>
#include <cstddef>

// =====================================================================
// LENet block: x = MHA(LN(q), LN(kv)) + q ; x = MHA(LN(x),LN(x)) + x ;
//              x = NoisyTop2MoE(LN(x)) + x
// Round 8:
//   a) K/V pre-split kernels (ksp_k/ksp_v): fp32 K,V -> (hi,lo) bf16,
//      PRE-SWIZZLED (slot q = part ^ (row&7)) so attn stages via linear
//      global_load_lds and reads conflict-floor b128 frags. Removes the
//      16x-redundant per-q-block split VALU from attn.
//   b) 2-barrier overlap in every MFMA loop: barrier -> ds_read frags
//      (-> MFMA using them) -> barrier -> issue NEXT tile gl16 -> rest
//      of compute. Round-7 issued loads then barrier'd immediately,
//      exposing full latency each step (why it was neutral).
//   c) out-proj split-K x2 (copy residual first, atomicAdd partials).
// Round 7: global_load_lds staging, linear LDS. Round 6: ffn2 split-K,
// fused QKV launch. Round 5: tcvt expert weights. Round 4: MFMA attn.
// Projections: split-bf16 (bf16x3) MFMA, ~4e-6 rel err, routing-safe.
// =====================================================================
#define JAX_THREEFRY_PARTITIONABLE 1

typedef unsigned short u16;
typedef unsigned int u32;
typedef __attribute__((ext_vector_type(8))) short bf16x8;   // 8 bf16 = 4 VGPR
typedef __attribute__((ext_vector_type(4))) float f32x4;

struct Ptr8 { u16* p[8]; };   // per-expert W^T bf16 buffers (by-value arg)

struct QkvArgs {              // fused QKV projection args (by-value)
  const u16* ah[3]; const u16* al[3];
  const u16* wh[3]; const u16* wl[3];
  const float* bias[3];
  float* c[3];
  int M[3];
};

__device__ __forceinline__ int imin_(int a, int b) { return a < b ? a : b; }

// async 16B global -> LDS (wave-uniform lds base + lane*16 semantics)
__device__ __forceinline__ void gl16_(const void* g, void* l) {
  __builtin_amdgcn_global_load_lds(
      (const __attribute__((address_space(1))) void*)g,
      (__attribute__((address_space(3))) void*)l, 16, 0, 0);
}

__device__ __forceinline__ u16 f2bf_(float f) {  // RNE float->bf16
  unsigned u = __float_as_uint(f);
  return (u16)((u + 0x7fffu + ((u >> 16) & 1u)) >> 16);
}
__device__ __forceinline__ float bf2f_(u16 h) {
  return __uint_as_float(((unsigned)h) << 16);
}

// split (a,b) into packed-u32 (hi,hi) and (lo,lo) bf16 pairs, low half = a
__device__ __forceinline__ void split2_(float a, float b, u32& hi, u32& lo) {
  u16 h0 = f2bf_(a), h1 = f2bf_(b);
  u16 l0 = f2bf_(a - bf2f_(h0)), l1 = f2bf_(b - bf2f_(h1));
  hi = (u32)h0 | ((u32)h1 << 16);
  lo = (u32)l0 | ((u32)l1 << 16);
}

union FragU {
  u32 w[4];
  uint4 q;
  bf16x8 v;
};

// ---------------- threefry2x32 (JAX-exact, 20 rounds) ----------------
__device__ __forceinline__ unsigned rotl32_(unsigned v, int d) {
  return (v << d) | (v >> (32 - d));
}

__device__ __forceinline__ void threefry2x32_(unsigned k0, unsigned k1,
                                              unsigned x0, unsigned x1,
                                              unsigned& o0, unsigned& o1) {
  unsigned ks2 = k0 ^ k1 ^ 0x1BD11BDAu;
  x0 += k0; x1 += k1;
#define TF_R(rot) { x0 += x1; x1 = rotl32_(x1, rot); x1 ^= x0; }
  TF_R(13) TF_R(15) TF_R(26) TF_R(6)
  x0 += k1;  x1 += ks2 + 1u;
  TF_R(17) TF_R(29) TF_R(16) TF_R(24)
  x0 += ks2; x1 += k0 + 2u;
  TF_R(13) TF_R(15) TF_R(26) TF_R(6)
  x0 += k0;  x1 += k1 + 3u;
  TF_R(17) TF_R(29) TF_R(16) TF_R(24)
  x0 += k1;  x1 += ks2 + 4u;
  TF_R(13) TF_R(15) TF_R(26) TF_R(6)
  x0 += ks2; x1 += k0 + 5u;
#undef TF_R
  o0 = x0; o1 = x1;
}

// XLA ErfInv32 (Giles polynomial) — matches lax.erf_inv on f32.
__device__ float erfinv_f32_(float x) {
  float w = -log1pf(-x * x);
  float p;
  if (w < 5.0f) {
    w -= 2.5f;
    p = 2.81022636e-08f;
    p = fmaf(p, w, 3.43273939e-07f);
    p = fmaf(p, w, -3.5233877e-06f);
    p = fmaf(p, w, -4.39150654e-06f);
    p = fmaf(p, w, 0.00021858087f);
    p = fmaf(p, w, -0.00125372503f);
    p = fmaf(p, w, -0.00417768164f);
    p = fmaf(p, w, 0.246640727f);
    p = fmaf(p, w, 1.50140941f);
  } else {
    w = sqrtf(w) - 3.0f;
    p = -0.000200214257f;
    p = fmaf(p, w, 0.000100950558f);
    p = fmaf(p, w, 0.00134934322f);
    p = fmaf(p, w, -0.00367342844f);
    p = fmaf(p, w, 0.00573950773f);
    p = fmaf(p, w, -0.0076224613f);
    p = fmaf(p, w, 0.00943887047f);
    p = fmaf(p, w, 1.00167406f);
    p = fmaf(p, w, 2.83297682f);
  }
  return p * x;
}

__device__ float bits_to_normal_(unsigned b) {
  const float lo = -0.99999994f;  // nextafter(-1, 0) in f32
  float f = __uint_as_float((b >> 9) | 0x3f800000u) - 1.0f;  // [0,1)
  float u = fmaxf(lo, f * 2.0f + lo);
  return 1.41421356237f * erfinv_f32_(u);
}

// normals for logits shape (2,1024,8) -> 16384 elems, key = (0,42)
__global__ __launch_bounds__(256) void noise_kernel(float* __restrict__ normals) {
  int i = blockIdx.x * 256 + threadIdx.x;
#if JAX_THREEFRY_PARTITIONABLE
  if (i < 16384) {
    unsigned o0, o1;
    threefry2x32_(0u, 42u, 0u, (unsigned)i, o0, o1);
    normals[i] = bits_to_normal_(o0 ^ o1);
  }
#else
  if (i < 8192) {
    unsigned o0, o1;
    threefry2x32_(0u, 42u, (unsigned)i, (unsigned)(i + 8192), o0, o1);
    normals[i] = bits_to_normal_(o0);
    normals[i + 8192] = bits_to_normal_(o1);
  }
#endif
}

// ---------------- block reduce (256 threads, wave64) -----------------
__device__ float block_reduce_sum_(float v) {
  for (int m = 1; m <= 32; m <<= 1) v += __shfl_xor(v, m, 64);
  __shared__ float red[4];
  int lane = threadIdx.x & 63, w = threadIdx.x >> 6;
  if (lane == 0) red[w] = v;
  __syncthreads();
  v = red[0] + red[1] + red[2] + red[3];
  __syncthreads();
  return v;
}

// ---------------- LayerNorm (fp32 out) -------------------------------
__global__ __launch_bounds__(256) void ln_kernel(
    const float* __restrict__ X, const float* __restrict__ g,
    const float* __restrict__ bta, float* __restrict__ Y) {
  int row = blockIdx.x;
  int t = threadIdx.x;
  const float4* xr = (const float4*)(X + (size_t)row * 1024);
  float4 v = xr[t];
  float s = v.x + v.y + v.z + v.w;
  s = block_reduce_sum_(s);
  float mean = s * (1.0f / 1024.0f);
  float dx = v.x - mean, dy = v.y - mean, dz = v.z - mean, dw = v.w - mean;
  float sq = dx * dx + dy * dy + dz * dz + dw * dw;
  sq = block_reduce_sum_(sq);
  float rstd = 1.0f / sqrtf(sq * (1.0f / 1024.0f) + 1e-5f);
  float4 gv = ((const float4*)g)[t];
  float4 bv = ((const float4*)bta)[t];
  float4 y;
  y.x = dx * rstd * gv.x + bv.x;
  y.y = dy * rstd * gv.y + bv.y;
  y.z = dz * rstd * gv.z + bv.z;
  y.w = dw * rstd * gv.w + bv.w;
  ((float4*)(Y + (size_t)row * 1024))[t] = y;
}

// ---------------- LayerNorm emitting split bf16 (hi,lo) --------------
__global__ __launch_bounds__(256) void ln_split_kernel(
    const float* __restrict__ X, const float* __restrict__ g,
    const float* __restrict__ bta, u16* __restrict__ Yh,
    u16* __restrict__ Yl) {
  int row = blockIdx.x;
  int t = threadIdx.x;
  const float4* xr = (const float4*)(X + (size_t)row * 1024);
  float4 v = xr[t];
  float s = v.x + v.y + v.z + v.w;
  s = block_reduce_sum_(s);
  float mean = s * (1.0f / 1024.0f);
  float dx = v.x - mean, dy = v.y - mean, dz = v.z - mean, dw = v.w - mean;
  float sq = dx * dx + dy * dy + dz * dz + dw * dw;
  sq = block_reduce_sum_(sq);
  float rstd = 1.0f / sqrtf(sq * (1.0f / 1024.0f) + 1e-5f);
  float4 gv = ((const float4*)g)[t];
  float4 bv = ((const float4*)bta)[t];
  float y[4];
  y[0] = dx * rstd * gv.x + bv.x;
  y[1] = dy * rstd * gv.y + bv.y;
  y[2] = dz * rstd * gv.z + bv.z;
  y[3] = dw * rstd * gv.w + bv.w;
  ushort4 h, l;
  u16* hp = (u16*)&h; u16* lp = (u16*)&l;
#pragma unroll
  for (int j = 0; j < 4; ++j) {
    u16 hh = f2bf_(y[j]);
    hp[j] = hh;
    lp[j] = f2bf_(y[j] - bf2f_(hh));
  }
  *(ushort4*)(Yh + (size_t)row * 1024 + t * 4) = h;
  *(ushort4*)(Yl + (size_t)row * 1024 + t * 4) = l;
}

// ---------------- fp32 -> (hi,lo) bf16 split, 4 elems/thread ---------
__global__ __launch_bounds__(256) void cvt_split_kernel(
    const float* __restrict__ src, u16* __restrict__ hi,
    u16* __restrict__ lo) {
  int i = (blockIdx.x * 256 + threadIdx.x) * 4;
  float4 v = *(const float4*)(src + i);
  float a[4] = {v.x, v.y, v.z, v.w};
  ushort4 h, l;
  u16* hp = (u16*)&h; u16* lp = (u16*)&l;
#pragma unroll
  for (int j = 0; j < 4; ++j) {
    u16 hh = f2bf_(a[j]);
    hp[j] = hh;
    lp[j] = f2bf_(a[j] - bf2f_(hh));
  }
  *(ushort4*)(hi + i) = h;
  *(ushort4*)(lo + i) = l;
}

// ---------- transpose+convert: fp32 [R][C] -> bf16 [C][R], 8 experts -
__global__ __launch_bounds__(256) void tcvt_kernel(
    const float* __restrict__ src, Ptr8 dst, int R, int C) {
  __shared__ float tile[64][65];
  const int e = blockIdx.z;
  const float* S = src + (size_t)e * R * C;
  u16* D = dst.p[e];
  const int c0 = blockIdx.x * 64, r0 = blockIdx.y * 64;
  const int t = threadIdx.x;
  const int tr = t >> 4, tc = (t & 15) * 4;
#pragma unroll
  for (int p = 0; p < 4; ++p) {
    float4 v = *(const float4*)(S + (size_t)(r0 + p * 16 + tr) * C + c0 + tc);
    tile[p * 16 + tr][tc + 0] = v.x;
    tile[p * 16 + tr][tc + 1] = v.y;
    tile[p * 16 + tr][tc + 2] = v.z;
    tile[p * 16 + tr][tc + 3] = v.w;
  }
  __syncthreads();
#pragma unroll
  for (int p = 0; p < 4; ++p) {
    int oc = p * 16 + tr;
    ushort4 o;
    o.x = f2bf_(tile[tc + 0][oc]);
    o.y = f2bf_(tile[tc + 1][oc]);
    o.z = f2bf_(tile[tc + 2][oc]);
    o.w = f2bf_(tile[tc + 3][oc]);
    *(ushort4*)(D + (size_t)(c0 + oc) * R + r0 + tc) = o;
  }
}

// ---------- K pre-split: fp32 proj K -> (hi,lo) bf16, pre-swizzled ---
// layout: [bh][kv][64 u16], 16B slot q = part ^ (kv&7), part = dh>>3.
__global__ __launch_bounds__(256) void ksp_k_kernel(
    const float* __restrict__ KP, u16* __restrict__ Kh,
    u16* __restrict__ Kl, int nkv) {
  const int bh = blockIdx.x;
  const int b = bh >> 4, h = bh & 15;
  const int kv0 = blockIdx.y * 64;
  const int t = threadIdx.x;
  const int kvl = t >> 2, dh0 = (t & 3) * 16;
  const int kv = kv0 + kvl;
  const float* src = KP + (size_t)(b * nkv + kv) * 1024 + h * 64 + dh0;
  float f[16];
  *(float4*)(f + 0)  = *(const float4*)(src + 0);
  *(float4*)(f + 4)  = *(const float4*)(src + 4);
  *(float4*)(f + 8)  = *(const float4*)(src + 8);
  *(float4*)(f + 12) = *(const float4*)(src + 12);
  size_t rowb = ((size_t)bh * nkv + kv) * 64;
#pragma unroll
  for (int pi = 0; pi < 2; ++pi) {
    int p = (t & 3) * 2 + pi;
    FragU hq, lq;
#pragma unroll
    for (int w = 0; w < 4; ++w)
      split2_(f[pi * 8 + 2 * w], f[pi * 8 + 2 * w + 1], hq.w[w], lq.w[w]);
    int q = p ^ (kvl & 7);
    *(uint4*)&Kh[rowb + q * 8] = hq.q;
    *(uint4*)&Kl[rowb + q * 8] = lq.q;
  }
}

// ---------- V pre-split transposed: [bh][dh][nkv] bf16, pre-swizzled -
// slot q (within 64-kv tile) = part ^ (dh&7), part = kv_local>>3.
__global__ __launch_bounds__(256) void ksp_v_kernel(
    const float* __restrict__ VP, u16* __restrict__ Vh,
    u16* __restrict__ Vl, int nkv) {
  __shared__ float tile[64][65];
  const int bh = blockIdx.x;
  const int b = bh >> 4, h = bh & 15;
  const int kv0 = blockIdx.y * 64;
  const int t = threadIdx.x;
  {
    const int kvl = t >> 2, dh0 = (t & 3) * 16;
    const float* src =
        VP + (size_t)(b * nkv + kv0 + kvl) * 1024 + h * 64 + dh0;
#pragma unroll
    for (int j = 0; j < 4; ++j) {
      float4 v = *(const float4*)(src + 4 * j);
      tile[kvl][dh0 + 4 * j + 0] = v.x;
      tile[kvl][dh0 + 4 * j + 1] = v.y;
      tile[kvl][dh0 + 4 * j + 2] = v.z;
      tile[kvl][dh0 + 4 * j + 3] = v.w;
    }
  }
  __syncthreads();
  const int dh = t >> 2;
  size_t rowb = ((size_t)bh * 64 + dh) * nkv + kv0;
#pragma unroll
  for (int pi = 0; pi < 2; ++pi) {
    int p = (t & 3) * 2 + pi;
    FragU hq, lq;
#pragma unroll
    for (int w = 0; w < 4; ++w)
      split2_(tile[p * 8 + 2 * w][dh], tile[p * 8 + 2 * w + 1][dh],
              hq.w[w], lq.w[w]);
    int q = p ^ (dh & 7);
    *(uint4*)&Vh[rowb + q * 8] = hq.q;
    *(uint4*)&Vl[rowb + q * 8] = lq.q;
  }
}

// ============ split-bf16 MFMA GEMM: C = A @ W^T + bias ===============
// 128x128 tile, BK=32, 4 waves, 48 MFMA/step (3-term split).
// 2-barrier overlap: barrier -> ds_read frags -> barrier -> issue next
// tile gl16 -> MFMA (loads fly under the MFMAs).
template<bool ATOMIC>
__device__ __forceinline__ void split_gemm_body_(
    const u16* __restrict__ Ah, const u16* __restrict__ Al,
    const u16* __restrict__ Wh, const u16* __restrict__ Wl,
    const float* __restrict__ bias, int addb, float* __restrict__ C,
    int m0, int n0, int N, int K, int kbeg, int klen) {
  __shared__ __align__(16) u16 Ahs[128 * 32];
  __shared__ __align__(16) u16 Als[128 * 32];
  __shared__ __align__(16) u16 Bhs[128 * 32];
  __shared__ __align__(16) u16 Bls[128 * 32];
  const int t = threadIdx.x;
  const int lane = t & 63, wv = t >> 6;
  const int wm = (wv & 1) * 64, wn = (wv >> 1) * 64;
  const int col = lane & 15, quad = lane >> 4;
  f32x4 acc[4][4] = {};
  const int r0 = t >> 2, kq = (t & 3) * 8;
  const u16* pah0 = Ah + (size_t)(m0 + r0) * K + kbeg + kq;
  const u16* pah1 = Ah + (size_t)(m0 + r0 + 64) * K + kbeg + kq;
  const u16* pal0 = Al + (size_t)(m0 + r0) * K + kbeg + kq;
  const u16* pal1 = Al + (size_t)(m0 + r0 + 64) * K + kbeg + kq;
  const u16* pwh0 = Wh + (size_t)(n0 + r0) * K + kbeg + kq;
  const u16* pwh1 = Wh + (size_t)(n0 + r0 + 64) * K + kbeg + kq;
  const u16* pwl0 = Wl + (size_t)(n0 + r0) * K + kbeg + kq;
  const u16* pwl1 = Wl + (size_t)(n0 + r0 + 64) * K + kbeg + kq;
  u16* lah0 = &Ahs[t * 8]; u16* lah1 = &Ahs[(t + 256) * 8];
  u16* lal0 = &Als[t * 8]; u16* lal1 = &Als[(t + 256) * 8];
  u16* lbh0 = &Bhs[t * 8]; u16* lbh1 = &Bhs[(t + 256) * 8];
  u16* lbl0 = &Bls[t * 8]; u16* lbl1 = &Bls[(t + 256) * 8];
#define SG_ISSUE() do { \
    gl16_(pah0, lah0); gl16_(pah1, lah1); \
    gl16_(pal0, lal0); gl16_(pal1, lal1); \
    gl16_(pwh0, lbh0); gl16_(pwh1, lbh1); \
    gl16_(pwl0, lbl0); gl16_(pwl1, lbl1); \
    pah0 += 32; pah1 += 32; pal0 += 32; pal1 += 32; \
    pwh0 += 32; pwh1 += 32; pwl0 += 32; pwl1 += 32; } while (0)
  SG_ISSUE();
  for (int k0 = 0; k0 < klen; k0 += 32) {
    __syncthreads();                       // tile resident
    bf16x8 afh[4], afl[4], bfh[4], bfl[4];
#pragma unroll
    for (int i = 0; i < 4; ++i) {
      afh[i] = *(const bf16x8*)&Ahs[(wm + i * 16 + col) * 32 + quad * 8];
      afl[i] = *(const bf16x8*)&Als[(wm + i * 16 + col) * 32 + quad * 8];
    }
#pragma unroll
    for (int j = 0; j < 4; ++j) {
      bfh[j] = *(const bf16x8*)&Bhs[(wn + j * 16 + col) * 32 + quad * 8];
      bfl[j] = *(const bf16x8*)&Bls[(wn + j * 16 + col) * 32 + quad * 8];
    }
    __syncthreads();                       // reads done; LDS free
    if (k0 + 32 < klen) SG_ISSUE();        // overlap with MFMAs below
#pragma unroll
    for (int i = 0; i < 4; ++i) {
#pragma unroll
      for (int j = 0; j < 4; ++j) {
        acc[i][j] = __builtin_amdgcn_mfma_f32_16x16x32_bf16(afh[i], bfh[j], acc[i][j], 0, 0, 0);
        acc[i][j] = __builtin_amdgcn_mfma_f32_16x16x32_bf16(afh[i], bfl[j], acc[i][j], 0, 0, 0);
        acc[i][j] = __builtin_amdgcn_mfma_f32_16x16x32_bf16(afl[i], bfh[j], acc[i][j], 0, 0, 0);
      }
    }
  }
#undef SG_ISSUE
  float bv[4];
#pragma unroll
  for (int j = 0; j < 4; ++j)
    bv[j] = (!ATOMIC || addb) ? bias[n0 + wn + j * 16 + col] : 0.0f;
#pragma unroll
  for (int i = 0; i < 4; ++i) {
#pragma unroll
    for (int rr = 0; rr < 4; ++rr) {
      int m = m0 + wm + i * 16 + quad * 4 + rr;
      float* crow = C + (size_t)m * N;
#pragma unroll
      for (int j = 0; j < 4; ++j) {
        int n = n0 + wn + j * 16 + col;
        float v = acc[i][j][rr] + bv[j];
        if (ATOMIC) atomicAdd(&crow[n], v);
        else crow[n] = v;
      }
    }
  }
}

// fused Q/K/V projections: blockIdx.z picks the projection.
__global__ __launch_bounds__(256) void split_gemm_qkv(QkvArgs a, int N, int K) {
  const int z = blockIdx.z;
  const int m0 = blockIdx.y * 128;
  if (m0 >= a.M[z]) return;
  split_gemm_body_<false>(a.ah[z], a.al[z], a.wh[z], a.wl[z], a.bias[z], 1,
                          a.c[z], m0, blockIdx.x * 128, N, K, 0, K);
}

// out-proj with split-K x2: C must be pre-filled with the residual;
// partials atomicAdd; bias added by ks==0 chunk only.
__global__ __launch_bounds__(256) void split_gemm_atomic(
    const u16* __restrict__ Ah, const u16* __restrict__ Al,
    const u16* __restrict__ Wh, const u16* __restrict__ Wl,
    const float* __restrict__ bias, float* __restrict__ C, int N, int K) {
  const int ks = blockIdx.z;
  split_gemm_body_<true>(Ah, Al, Wh, Wl, bias, ks == 0 ? 1 : 0, C,
                         blockIdx.y * 128, blockIdx.x * 128, N, K,
                         ks * (K >> 1), K >> 1);
}

// ============ flash attention, split-bf16 MFMA, DH=64 ================
// K/V pre-split+pre-swizzled in global (ksp kernels); staging is pure
// global_load_lds (linear dest). Frag reads XOR-deswizzle:
//   addr = row*64 + ((ks*4+quad) ^ (row&7))*8   (row&7 == col&7).
// S^T = K @ Q^T swapped operands; lane-local softmax rows; shuffle
// repack C-layout -> A-frag; PV from register-preloaded V frags.
// 2-barrier loop: barrier -> K frags+S^T, V frags -> barrier -> issue
// next tile gl16 -> softmax/repack/PV (loads overlap compute).
__global__ __launch_bounds__(256) void attn_kernel(
    const float* __restrict__ QP, const u16* __restrict__ Khg,
    const u16* __restrict__ Klg, const u16* __restrict__ Vhg,
    const u16* __restrict__ Vlg, u16* __restrict__ AOh,
    u16* __restrict__ AOl, int nq, int nkv) {
  __shared__ __align__(16) u16 Ksh[64 * 64];
  __shared__ __align__(16) u16 Ksl[64 * 64];
  __shared__ __align__(16) u16 Vth[64 * 64];
  __shared__ __align__(16) u16 Vtl[64 * 64];
  const int t = threadIdx.x;
  const int lane = t & 63, wv = t >> 6;
  const int col = lane & 15, quad = lane >> 4;
  const int bh = blockIdx.x;
  const int b = bh >> 4, h = bh & 15;
  const int q0 = blockIdx.y * 64;
  const int wq0 = wv * 16;
  const int s1 = t + 256;
  const size_t krow = (size_t)bh * nkv;
  const size_t vbase = (size_t)bh * 64 * nkv;
  const size_t voff0 = (size_t)(t >> 3) * nkv + (t & 7) * 8;
  const size_t voff1 = (size_t)(s1 >> 3) * nkv + (s1 & 7) * 8;

  // prologue: issue tile 0 (flies under the Q preload)
  {
    const u16* kb = Khg + krow * 64;
    const u16* lb = Klg + krow * 64;
    gl16_(kb + t * 8, &Ksh[t * 8]);
    gl16_(kb + s1 * 8, &Ksh[s1 * 8]);
    gl16_(lb + t * 8, &Ksl[t * 8]);
    gl16_(lb + s1 * 8, &Ksl[s1 * 8]);
    const u16* vb = Vhg + vbase;
    const u16* wb = Vlg + vbase;
    gl16_(vb + voff0, &Vth[t * 8]);
    gl16_(vb + voff1, &Vth[s1 * 8]);
    gl16_(wb + voff0, &Vtl[t * 8]);
    gl16_(wb + voff1, &Vtl[s1 * 8]);
  }

  // ---- preload this wave's Q fragments (B operand), scaled 1/8 ----
  bf16x8 qbh[2], qbl[2];
  {
    const float* qsrc =
        QP + (size_t)(b * nq + q0 + wq0 + col) * 1024 + h * 64 + quad * 8;
#pragma unroll
    for (int ks = 0; ks < 2; ++ks) {
      float4 f0 = *(const float4*)(qsrc + ks * 32);
      float4 f1 = *(const float4*)(qsrc + ks * 32 + 4);
      float qf[8] = {f0.x, f0.y, f0.z, f0.w, f1.x, f1.y, f1.z, f1.w};
      FragU uh, ul;
#pragma unroll
      for (int w = 0; w < 4; ++w)
        split2_(qf[2 * w] * 0.125f, qf[2 * w + 1] * 0.125f, uh.w[w], ul.w[w]);
      qbh[ks] = uh.v;
      qbl[ks] = ul.v;
    }
  }

  f32x4 o[4] = {};
  float mi = -INFINITY, li = 0.0f;

  for (int kv0 = 0; kv0 < nkv; kv0 += 64) {
    __syncthreads();   // tile resident (drains gl16)

    // ---- K frags + S^T = K @ Q^T (3-term split) ----
    f32x4 st[4] = {};
#pragma unroll
    for (int ks = 0; ks < 2; ++ks) {
      bf16x8 kah[4], kal[4];
#pragma unroll
      for (int i = 0; i < 4; ++i) {
        int addr = (i * 16 + col) * 64 + (((ks << 2) + quad) ^ (col & 7)) * 8;
        kah[i] = *(const bf16x8*)&Ksh[addr];
        kal[i] = *(const bf16x8*)&Ksl[addr];
      }
#pragma unroll
      for (int i = 0; i < 4; ++i) {
        st[i] = __builtin_amdgcn_mfma_f32_16x16x32_bf16(kah[i], qbh[ks], st[i], 0, 0, 0);
        st[i] = __builtin_amdgcn_mfma_f32_16x16x32_bf16(kah[i], qbl[ks], st[i], 0, 0, 0);
        st[i] = __builtin_amdgcn_mfma_f32_16x16x32_bf16(kal[i], qbh[ks], st[i], 0, 0, 0);
      }
    }
    // ---- V frags to registers ----
    bf16x8 vfh[2][4], vfl[2][4];
#pragma unroll
    for (int ks = 0; ks < 2; ++ks) {
#pragma unroll
      for (int j = 0; j < 4; ++j) {
        int addr = (j * 16 + col) * 64 + (((ks << 2) + quad) ^ (col & 7)) * 8;
        vfh[ks][j] = *(const bf16x8*)&Vth[addr];
        vfl[ks][j] = *(const bf16x8*)&Vtl[addr];
      }
    }
    __syncthreads();   // all LDS reads done; safe to overwrite
    if (kv0 + 64 < nkv) {
      const u16* kb = Khg + (krow + kv0 + 64) * 64;
      const u16* lb = Klg + (krow + kv0 + 64) * 64;
      gl16_(kb + t * 8, &Ksh[t * 8]);
      gl16_(kb + s1 * 8, &Ksh[s1 * 8]);
      gl16_(lb + t * 8, &Ksl[t * 8]);
      gl16_(lb + s1 * 8, &Ksl[s1 * 8]);
      const u16* vb = Vhg + vbase + kv0 + 64;
      const u16* wb = Vlg + vbase + kv0 + 64;
      gl16_(vb + voff0, &Vth[t * 8]);
      gl16_(vb + voff1, &Vth[s1 * 8]);
      gl16_(wb + voff0, &Vtl[t * 8]);
      gl16_(wb + voff1, &Vtl[s1 * 8]);
    }

    // ---- online softmax: full score row is lane-local (+quad xor) ----
    float tmax = st[0][0];
#pragma unroll
    for (int i = 0; i < 4; ++i)
#pragma unroll
      for (int r = 0; r < 4; ++r) tmax = fmaxf(tmax, st[i][r]);
    tmax = fmaxf(tmax, __shfl_xor(tmax, 16, 64));
    tmax = fmaxf(tmax, __shfl_xor(tmax, 32, 64));
    float mnew = fmaxf(mi, tmax);
    float alpha = __expf(mi - mnew);
    float tsum = 0.0f;
#pragma unroll
    for (int i = 0; i < 4; ++i) {
#pragma unroll
      for (int r = 0; r < 4; ++r) {
        float p = __expf(st[i][r] - mnew);
        st[i][r] = p;
        tsum += p;
      }
    }
    tsum += __shfl_xor(tsum, 16, 64);
    tsum += __shfl_xor(tsum, 32, 64);
    li = li * alpha + tsum;
    mi = mnew;
    float alr[4];
#pragma unroll
    for (int r = 0; r < 4; ++r)
      alr[r] = __shfl(alpha, (lane & 48) | (quad * 4 + r), 64);
#pragma unroll
    for (int j = 0; j < 4; ++j)
#pragma unroll
      for (int r = 0; r < 4; ++r) o[j][r] *= alr[r];

    // ---- P -> split bf16, pack pairs, redistribute to A-frag layout ----
    u32 pkh[4][2], pkl[4][2];
#pragma unroll
    for (int i = 0; i < 4; ++i)
#pragma unroll
      for (int w = 0; w < 2; ++w)
        split2_(st[i][2 * w], st[i][2 * w + 1], pkh[i][w], pkl[i][w]);
    u32 APh[2][4], APl[2][4];
    const int par = quad >> 1;
#pragma unroll
    for (int i = 0; i < 4; ++i) {
#pragma unroll
      for (int w01 = 0; w01 < 2; ++w01) {
#pragma unroll
        for (int dw = 0; dw < 2; ++dw) {
          int src = (((2 * quad + dw) & 3) << 4) | col;
          u32 vh = (u32)__shfl((int)pkh[i][w01], src, 64);
          u32 vl = (u32)__shfl((int)pkl[i][w01], src, 64);
          if ((i & 1) == par) {
            APh[i >> 1][dw * 2 + w01] = vh;
            APl[i >> 1][dw * 2 + w01] = vl;
          }
        }
      }
    }

    // ---- O += P @ V (3-term split), V from registers ----
#pragma unroll
    for (int ks = 0; ks < 2; ++ks) {
      FragU fh, fl;
#pragma unroll
      for (int w = 0; w < 4; ++w) { fh.w[w] = APh[ks][w]; fl.w[w] = APl[ks][w]; }
      bf16x8 pah = fh.v, pal = fl.v;
#pragma unroll
      for (int j = 0; j < 4; ++j) {
        o[j] = __builtin_amdgcn_mfma_f32_16x16x32_bf16(pah, vfh[ks][j], o[j], 0, 0, 0);
        o[j] = __builtin_amdgcn_mfma_f32_16x16x32_bf16(pah, vfl[ks][j], o[j], 0, 0, 0);
        o[j] = __builtin_amdgcn_mfma_f32_16x16x32_bf16(pal, vfh[ks][j], o[j], 0, 0, 0);
      }
    }
  }

  // ---- epilogue: 1/l per row, emit (hi,lo) split bf16 ----
  float inv = 1.0f / li;
  float ivr[4];
#pragma unroll
  for (int r = 0; r < 4; ++r)
    ivr[r] = __shfl(inv, (lane & 48) | (quad * 4 + r), 64);
#pragma unroll
  for (int r = 0; r < 4; ++r) {
    size_t base =
        (size_t)(b * nq + q0 + wq0 + quad * 4 + r) * 1024 + h * 64 + col;
#pragma unroll
    for (int j = 0; j < 4; ++j) {
      float v = o[j][r] * ivr[r];
      u16 hh = f2bf_(v);
      AOh[base + j * 16] = hh;
      AOl[base + j * 16] = f2bf_(v - bf2f_(hh));
    }
  }
}

// ---------------- router: logits & noise_logits (N=8 each) -----------
__global__ __launch_bounds__(256) void router_kernel(
    const float* __restrict__ xm, const float* __restrict__ rw,
    const float* __restrict__ rb, const float* __restrict__ nw,
    const float* __restrict__ nb, float* __restrict__ logits,
    float* __restrict__ nlogits) {
  int row = blockIdx.x, t = threadIdx.x;
  const float* x = xm + (size_t)row * 1024;
  float accl[8] = {}, accn[8] = {};
  for (int d = t; d < 1024; d += 256) {
    float xv = x[d];
#pragma unroll
    for (int e = 0; e < 8; ++e) {
      accl[e] += xv * rw[e * 1024 + d];
      accn[e] += xv * nw[e * 1024 + d];
    }
  }
  __shared__ float red[16][4];
  int lane = t & 63, w = t >> 6;
#pragma unroll
  for (int e = 0; e < 8; ++e) {
    float v = accl[e];
    for (int m = 1; m <= 32; m <<= 1) v += __shfl_xor(v, m, 64);
    if (lane == 0) red[e][w] = v;
    float v2 = accn[e];
    for (int m = 1; m <= 32; m <<= 1) v2 += __shfl_xor(v2, m, 64);
    if (lane == 0) red[8 + e][w] = v2;
  }
  __syncthreads();
  if (t < 8)
    logits[row * 8 + t] = red[t][0] + red[t][1] + red[t][2] + red[t][3] + rb[t];
  else if (t < 16)
    nlogits[row * 8 + t - 8] =
        red[t][0] + red[t][1] + red[t][2] + red[t][3] + nb[t - 8];
}

// ---------------- routing: noisy top-2, probs, expert counts ---------
__global__ __launch_bounds__(256) void route_kernel(
    const float* __restrict__ logits, const float* __restrict__ nlogits,
    const float* __restrict__ normals, int* __restrict__ routei,
    float* __restrict__ routep, int* __restrict__ cnt) {
  int bt = blockIdx.x * 256 + threadIdx.x;
  if (bt >= 2048) return;
  float noisy[8];
#pragma unroll
  for (int e = 0; e < 8; ++e) {
    float nl = nlogits[bt * 8 + e];
    float sp = fmaxf(nl, 0.0f) + log1pf(expf(-fabsf(nl)));  // softplus
    noisy[e] = logits[bt * 8 + e] + normals[bt * 8 + e] * sp;
  }
  int i1 = 0; float n1 = noisy[0];
#pragma unroll
  for (int e = 1; e < 8; ++e) if (noisy[e] > n1) { n1 = noisy[e]; i1 = e; }
  int i2 = -1; float n2 = -INFINITY;
#pragma unroll
  for (int e = 0; e < 8; ++e)
    if (e != i1 && noisy[e] > n2) { n2 = noisy[e]; i2 = e; }
  float e2 = expf(n2 - n1);
  float denom = 1.0f + e2;
  routei[bt * 2 + 0] = i1; routei[bt * 2 + 1] = i2;
  routep[bt * 2 + 0] = 1.0f / denom; routep[bt * 2 + 1] = e2 / denom;
  atomicAdd(&cnt[i1], 1);
  atomicAdd(&cnt[i2], 1);
}

__global__ void zero_kernel(int* __restrict__ cnt) {
  if (threadIdx.x < 8) cnt[threadIdx.x] = 0;
}

__global__ void offs_kernel(const int* __restrict__ cnt, int* __restrict__ offs,
                            int* __restrict__ fill) {
  if (threadIdx.x == 0 && blockIdx.x == 0) {
    int o = 0;
    for (int e = 0; e < 8; ++e) { offs[e] = o; o += cnt[e]; fill[e] = 0; }
  }
}

__global__ __launch_bounds__(256) void fill_kernel(
    const int* __restrict__ routei, const float* __restrict__ routep,
    const int* __restrict__ offs, int* __restrict__ fill,
    int* __restrict__ alist, float* __restrict__ aprob) {
  int bt = blockIdx.x * 256 + threadIdx.x;
  if (bt >= 2048) return;
#pragma unroll
  for (int s = 0; s < 2; ++s) {
    int e = routei[bt * 2 + s];
    int pos = offs[e] + atomicAdd(&fill[e], 1);
    alist[pos] = bt;
    aprob[pos] = routep[bt * 2 + s];
  }
}

__global__ __launch_bounds__(256) void copy_kernel(const float* __restrict__ src,
                                                   float* __restrict__ dst) {
  int i = blockIdx.x * 256 + threadIdx.x;
  ((float4*)dst)[i] = ((const float4*)src)[i];
}

// fp32 -> bf16 convert (hi only), 4 elems/thread
__global__ __launch_bounds__(256) void f2bf_kernel(const float* __restrict__ src,
                                                   u16* __restrict__ dst) {
  int i = (blockIdx.x * 256 + threadIdx.x) * 4;
  float4 v = *(const float4*)(src + i);
  ushort4 o;
  o.x = f2bf_(v.x); o.y = f2bf_(v.y); o.z = f2bf_(v.z); o.w = f2bf_(v.w);
  *(ushort4*)(dst + i) = o;
}

__device__ __forceinline__ float gelu_exact_(float x) {
  return 0.5f * x * (1.0f + erff(x * 0.70710678f));
}

// ===================== bf16 MFMA expert GEMMs ========================
// NT on pre-transposed bf16 W^T; 2-barrier overlap staging.
__global__ __launch_bounds__(256) void ffn1_mfma(
    const u16* __restrict__ Xb, Ptr8 w1t, const float* __restrict__ B1,
    u16* __restrict__ H, const int* __restrict__ alist,
    const int* __restrict__ cnt, const int* __restrict__ offs) {
  const int e = blockIdx.z;
  const int ce = cnt[e];
  const int m0 = blockIdx.y * 128;
  if (m0 >= ce) return;
  const int off = offs[e];
  const int n0 = blockIdx.x * 128;
  const u16* __restrict__ WT = w1t.p[e];   // [4096][1024] bf16 k-contig
  __shared__ __align__(16) u16 As[128 * 32];
  __shared__ __align__(16) u16 Bs[128 * 32];
  const int t = threadIdx.x;
  const int lane = t & 63, wv = t >> 6;
  const int wm = (wv & 1) * 64, wn = (wv >> 1) * 64;
  const int col = lane & 15, quad = lane >> 4;
  f32x4 acc[4][4] = {};
  const int r0 = t >> 2, kq = (t & 3) * 8;
  const int arow0 = alist[off + imin_(m0 + r0, ce - 1)];
  const int arow1 = alist[off + imin_(m0 + r0 + 64, ce - 1)];
  const u16* pa0 = Xb + (size_t)arow0 * 1024 + kq;
  const u16* pa1 = Xb + (size_t)arow1 * 1024 + kq;
  const u16* pw0 = WT + (size_t)(n0 + r0) * 1024 + kq;
  const u16* pw1 = WT + (size_t)(n0 + r0 + 64) * 1024 + kq;
  u16* la0 = &As[t * 8]; u16* la1 = &As[(t + 256) * 8];
  u16* lb0 = &Bs[t * 8]; u16* lb1 = &Bs[(t + 256) * 8];
#define F1_ISSUE() do { \
    gl16_(pa0, la0); gl16_(pa1, la1); gl16_(pw0, lb0); gl16_(pw1, lb1); \
    pa0 += 32; pa1 += 32; pw0 += 32; pw1 += 32; } while (0)
  F1_ISSUE();
  for (int k0 = 0; k0 < 1024; k0 += 32) {
    __syncthreads();
    bf16x8 af[4], bf[4];
#pragma unroll
    for (int i = 0; i < 4; ++i)
      af[i] = *(const bf16x8*)&As[(wm + i * 16 + col) * 32 + quad * 8];
#pragma unroll
    for (int j = 0; j < 4; ++j)
      bf[j] = *(const bf16x8*)&Bs[(wn + j * 16 + col) * 32 + quad * 8];
    __syncthreads();
    if (k0 + 32 < 1024) F1_ISSUE();
#pragma unroll
    for (int i = 0; i < 4; ++i)
#pragma unroll
      for (int j = 0; j < 4; ++j)
        acc[i][j] = __builtin_amdgcn_mfma_f32_16x16x32_bf16(af[i], bf[j], acc[i][j], 0, 0, 0);
  }
#undef F1_ISSUE
#pragma unroll
  for (int j = 0; j < 4; ++j) {
    int n = n0 + wn + j * 16 + col;
    float bv = B1[(size_t)e * 4096 + n];
#pragma unroll
    for (int i = 0; i < 4; ++i) {
#pragma unroll
      for (int r2 = 0; r2 < 4; ++r2) {
        int m = m0 + wm + i * 16 + quad * 4 + r2;
        if (m < ce) {
          float v = gelu_exact_(acc[i][j][r2] + bv);
          H[(size_t)(off + m) * 4096 + n] = f2bf_(v);
        }
      }
    }
  }
}

// ffn2 with split-K x4: blockIdx.y = (m-tile << 2) | ksplit.
__global__ __launch_bounds__(256) void ffn2_mfma(
    const u16* __restrict__ H, Ptr8 w2t, const float* __restrict__ B2,
    float* __restrict__ Out, const int* __restrict__ alist,
    const float* __restrict__ aprob, const int* __restrict__ cnt,
    const int* __restrict__ offs) {
  const int e = blockIdx.z;
  const int ce = cnt[e];
  const int mt = blockIdx.y >> 2, ks = blockIdx.y & 3;
  const int m0 = mt * 128;
  if (m0 >= ce) return;
  const int off = offs[e];
  const int n0 = blockIdx.x * 128;
  const u16* __restrict__ WT = w2t.p[e];   // [1024][4096] bf16 k-contig
  __shared__ __align__(16) u16 As[128 * 32];
  __shared__ __align__(16) u16 Bs[128 * 32];
  const int t = threadIdx.x;
  const int lane = t & 63, wv = t >> 6;
  const int wm = (wv & 1) * 64, wn = (wv >> 1) * 64;
  const int col = lane & 15, quad = lane >> 4;
  f32x4 acc[4][4] = {};
  const int r0 = t >> 2, kq = (t & 3) * 8;
  const u16* pa0 =
      H + (size_t)(off + imin_(m0 + r0, ce - 1)) * 4096 + ks * 1024 + kq;
  const u16* pa1 =
      H + (size_t)(off + imin_(m0 + r0 + 64, ce - 1)) * 4096 + ks * 1024 + kq;
  const u16* pw0 = WT + (size_t)(n0 + r0) * 4096 + ks * 1024 + kq;
  const u16* pw1 = WT + (size_t)(n0 + r0 + 64) * 4096 + ks * 1024 + kq;
  u16* la0 = &As[t * 8]; u16* la1 = &As[(t + 256) * 8];
  u16* lb0 = &Bs[t * 8]; u16* lb1 = &Bs[(t + 256) * 8];
#define F2_ISSUE() do { \
    gl16_(pa0, la0); gl16_(pa1, la1); gl16_(pw0, lb0); gl16_(pw1, lb1); \
    pa0 += 32; pa1 += 32; pw0 += 32; pw1 += 32; } while (0)
  F2_ISSUE();
  for (int k0 = 0; k0 < 1024; k0 += 32) {
    __syncthreads();
    bf16x8 af[4], bf[4];
#pragma unroll
    for (int i = 0; i < 4; ++i)
      af[i] = *(const bf16x8*)&As[(wm + i * 16 + col) * 32 + quad * 8];
#pragma unroll
    for (int j = 0; j < 4; ++j)
      bf[j] = *(const bf16x8*)&Bs[(wn + j * 16 + col) * 32 + quad * 8];
    __syncthreads();
    if (k0 + 32 < 1024) F2_ISSUE();
#pragma unroll
    for (int i = 0; i < 4; ++i)
#pragma unroll
      for (int j = 0; j < 4; ++j)
        acc[i][j] = __builtin_amdgcn_mfma_f32_16x16x32_bf16(af[i], bf[j], acc[i][j], 0, 0, 0);
  }
#undef F2_ISSUE
  float bv[4];
#pragma unroll
  for (int j = 0; j < 4; ++j)
    bv[j] = (ks == 0) ? B2[(size_t)e * 1024 + n0 + wn + j * 16 + col] : 0.0f;
#pragma unroll
  for (int i = 0; i < 4; ++i) {
#pragma unroll
    for (int r2 = 0; r2 < 4; ++r2) {
      int m = m0 + wm + i * 16 + quad * 4 + r2;
      if (m < ce) {
        int aidx = off + m;
        int tok = alist[aidx];
        float p = aprob[aidx];
        float* orow = Out + (size_t)tok * 1024;
#pragma unroll
        for (int j = 0; j < 4; ++j) {
          int n = n0 + wn + j * 16 + col;
          atomicAdd(&orow[n], p * (acc[i][j][r2] + bv[j]));
        }
      }
    }
  }
}

// =====================================================================
extern "C" void kernel_launch(void* const* d_in, const int* in_sizes, int n_in,
                              void* d_out, int out_size, void* d_ws, size_t ws_size,
                              hipStream_t stream) {
  (void)in_sizes; (void)n_in; (void)out_size; (void)ws_size;
  const float* q        = (const float*)d_in[0];
  const float* kv       = (const float*)d_in[1];
  const float* ln_cq_g  = (const float*)d_in[2];
  const float* ln_cq_b  = (const float*)d_in[3];
  const float* ln_ckv_g = (const float*)d_in[4];
  const float* ln_ckv_b = (const float*)d_in[5];
  const float* ln_s_g   = (const float*)d_in[6];
  const float* ln_s_b   = (const float*)d_in[7];
  const float* ln_m_g   = (const float*)d_in[8];
  const float* ln_m_b   = (const float*)d_in[9];
  const float* ca_in_w  = (const float*)d_in[10];
  const float* ca_in_b  = (const float*)d_in[11];
  const float* ca_out_w = (const float*)d_in[12];
  const float* ca_out_b = (const float*)d_in[13];
  const float* sa_in_w  = (const float*)d_in[14];
  const float* sa_in_b  = (const float*)d_in[15];
  const float* sa_out_w = (const float*)d_in[16];
  const float* sa_out_b = (const float*)d_in[17];
  const float* moe_rw   = (const float*)d_in[18];
  const float* moe_rb   = (const float*)d_in[19];
  const float* moe_nw   = (const float*)d_in[20];
  const float* moe_nb   = (const float*)d_in[21];
  const float* moe_w1   = (const float*)d_in[22];
  const float* moe_b1   = (const float*)d_in[23];
  const float* moe_w2   = (const float*)d_in[24];
  const float* moe_b2   = (const float*)d_in[25];
  float* out = (float*)d_out;

  // -------- workspace layout (floats). Peak ~112.5 MB. --------
  float* ws = (float*)d_ws;
  const size_t MEG = 1u << 20;
  float* x1   = ws;               // 2M fl
  float* x2   = ws + 2 * MEG;     // 2M fl
  float* xm   = ws + 4 * MEG;     // 2M fl
  u16*   aoh  = (u16*)(ws + 6 * MEG);  // 2M el (attn out hi)
  u16*   aol  = (u16*)(ws + 7 * MEG);  // 2M el (attn out lo)
  float* misc = ws + 8 * MEG;
  float* normals = misc;                      // 16384
  float* logits  = misc + 16384;              // 16384
  float* nlogits = misc + 32768;              // 16384
  float* routep  = misc + 49152;              // 4096
  float* aprob   = misc + 53248;              // 4096
  int*   routei  = (int*)(misc + 57344);      // 4096
  int*   alist   = (int*)(misc + 61440);      // 4096
  int*   cnt     = (int*)(misc + 65536);      // 8
  int*   offs    = cnt + 8;                   // 8
  int*   fillc   = cnt + 16;                  // 8
  float* RA = ws + 8 * MEG + 131072;          // 20M fl, phase-reused
  // attn phases:
  u16*   w1h = (u16*)RA;                    // 3M el (in-proj weights hi)
  u16*   w1l = (u16*)(RA + (3 * MEG) / 2);  // 3M el
  u16*   w2h = (u16*)(RA + 3 * MEG);        // 1M el (out-proj hi)
  u16*   w2l = (u16*)(RA + 3 * MEG + MEG / 2);
  u16*   a1h = (u16*)(RA + 4 * MEG);        // 2M el (lnq / xs hi)
  u16*   a1l = (u16*)(RA + 5 * MEG);
  u16*   a2h = (u16*)(RA + 6 * MEG);        // 4M el (lnkv hi; cross only)
  u16*   a2l = (u16*)(RA + 8 * MEG);
  float* qp  = RA + 10 * MEG;               // 2M fl
  float* kp  = RA + 12 * MEG;               // 4M fl (self: 2M)
  float* vp  = RA + 16 * MEG;               // 4M fl (self: 2M)
  // K/V pre-split buffers (dead regions after the QKV GEMM of a phase):
  //   ksph over w1 (RA+0..2M fl), kspl over a1 (RA+4..6M),
  //   vsph/vspl over a2 (RA+6..8M / 8..10M). Each 8MB max (cross).
  u16*   ksph = (u16*)RA;
  u16*   kspl = (u16*)(RA + 4 * MEG);
  u16*   vsph = (u16*)(RA + 6 * MEG);
  u16*   vspl = (u16*)(RA + 8 * MEG);
  // moe phase:
  u16*   xb  = (u16*)RA;                    // 2M el bf16
  u16*   hb  = (u16*)(RA + 1 * MEG);        // 16M el bf16 (ends RA+9M fl)
  Ptr8 wt;
  wt.p[0] = (u16*)(RA + 9 * MEG);
  wt.p[1] = (u16*)(RA + 11 * MEG);
  wt.p[2] = (u16*)(RA + 13 * MEG);
  wt.p[3] = (u16*)(RA + 15 * MEG);
  wt.p[4] = (u16*)(RA + 17 * MEG);
  wt.p[5] = (u16*)x1;
  wt.p[6] = (u16*)xm;
  wt.p[7] = (u16*)(ws + 6 * MEG);

  dim3 blk(256);

  zero_kernel<<<dim3(1), blk, 0, stream>>>(cnt);
  noise_kernel<<<dim3(64), blk, 0, stream>>>(normals);

  // ---- cross attention ----
  cvt_split_kernel<<<dim3(3072), blk, 0, stream>>>(ca_in_w, w1h, w1l);
  cvt_split_kernel<<<dim3(1024), blk, 0, stream>>>(ca_out_w, w2h, w2l);
  ln_split_kernel<<<dim3(2048), blk, 0, stream>>>(q, ln_cq_g, ln_cq_b, a1h, a1l);
  ln_split_kernel<<<dim3(4096), blk, 0, stream>>>(kv, ln_ckv_g, ln_ckv_b, a2h, a2l);
  {
    QkvArgs qa;
    qa.ah[0] = a1h; qa.al[0] = a1l;
    qa.ah[1] = a2h; qa.al[1] = a2l;
    qa.ah[2] = a2h; qa.al[2] = a2l;
    for (int z = 0; z < 3; ++z) {
      qa.wh[z] = w1h + (size_t)z * MEG;
      qa.wl[z] = w1l + (size_t)z * MEG;
      qa.bias[z] = ca_in_b + z * 1024;
    }
    qa.c[0] = qp; qa.c[1] = kp; qa.c[2] = vp;
    qa.M[0] = 2048; qa.M[1] = 4096; qa.M[2] = 4096;
    split_gemm_qkv<<<dim3(8, 32, 3), blk, 0, stream>>>(qa, 1024, 1024);
  }
  ksp_k_kernel<<<dim3(32, 32), blk, 0, stream>>>(kp, ksph, kspl, 2048);
  ksp_v_kernel<<<dim3(32, 32), blk, 0, stream>>>(vp, vsph, vspl, 2048);
  attn_kernel<<<dim3(32, 16), blk, 0, stream>>>(qp, ksph, kspl, vsph, vspl,
                                                aoh, aol, 1024, 2048);
  copy_kernel<<<dim3(2048), blk, 0, stream>>>(q, x1);  // residual base
  split_gemm_atomic<<<dim3(8, 16, 2), blk, 0, stream>>>(
      aoh, aol, w2h, w2l, ca_out_b, x1, 1024, 1024);

  // ---- self attention ----
  cvt_split_kernel<<<dim3(3072), blk, 0, stream>>>(sa_in_w, w1h, w1l);
  cvt_split_kernel<<<dim3(1024), blk, 0, stream>>>(sa_out_w, w2h, w2l);
  ln_split_kernel<<<dim3(2048), blk, 0, stream>>>(x1, ln_s_g, ln_s_b, a1h, a1l);
  {
    QkvArgs qa;
    for (int z = 0; z < 3; ++z) {
      qa.ah[z] = a1h; qa.al[z] = a1l;
      qa.wh[z] = w1h + (size_t)z * MEG;
      qa.wl[z] = w1l + (size_t)z * MEG;
      qa.bias[z] = sa_in_b + z * 1024;
      qa.M[z] = 2048;
    }
    qa.c[0] = qp; qa.c[1] = kp; qa.c[2] = vp;
    split_gemm_qkv<<<dim3(8, 16, 3), blk, 0, stream>>>(qa, 1024, 1024);
  }
  ksp_k_kernel<<<dim3(32, 16), blk, 0, stream>>>(kp, ksph, kspl, 1024);
  ksp_v_kernel<<<dim3(32, 16), blk, 0, stream>>>(vp, vsph, vspl, 1024);
  attn_kernel<<<dim3(32, 16), blk, 0, stream>>>(qp, ksph, kspl, vsph, vspl,
                                                aoh, aol, 1024, 1024);
  copy_kernel<<<dim3(2048), blk, 0, stream>>>(x1, x2);  // residual base
  split_gemm_atomic<<<dim3(8, 16, 2), blk, 0, stream>>>(
      aoh, aol, w2h, w2l, sa_out_b, x2, 1024, 1024);

  // ---- MoE ----
  ln_kernel<<<dim3(2048), blk, 0, stream>>>(x2, ln_m_g, ln_m_b, xm);
  f2bf_kernel<<<dim3(2048), blk, 0, stream>>>(xm, xb);
  router_kernel<<<dim3(2048), blk, 0, stream>>>(xm, moe_rw, moe_rb, moe_nw, moe_nb, logits, nlogits);
  route_kernel<<<dim3(8), blk, 0, stream>>>(logits, nlogits, normals, routei, routep, cnt);
  offs_kernel<<<dim3(1), blk, 0, stream>>>(cnt, offs, fillc);
  fill_kernel<<<dim3(8), blk, 0, stream>>>(routei, routep, offs, fillc, alist, aprob);
  copy_kernel<<<dim3(2048), blk, 0, stream>>>(x2, out);  // residual base
  // W1 [e][1024][4096] -> w1T [e][4096][1024] bf16 (x1/xm/aoh dead now)
  tcvt_kernel<<<dim3(64, 16, 8), blk, 0, stream>>>(moe_w1, wt, 1024, 4096);
  ffn1_mfma<<<dim3(32, 16, 8), blk, 0, stream>>>(xb, wt, moe_b1, hb, alist, cnt, offs);
  // W2 [e][4096][1024] -> w2T [e][1024][4096] bf16 (reuses same buffers)
  tcvt_kernel<<<dim3(16, 64, 8), blk, 0, stream>>>(moe_w2, wt, 4096, 1024);
  ffn2_mfma<<<dim3(8, 64, 8), blk, 0, stream>>>(hb, wt, moe_b2, out, alist, aprob, cnt, offs);
}